// Round 12
// baseline (2420.510 us; speedup 1.0000x reference)
//
#include <hip/hip_runtime.h>
#include <math.h>

#define N_NODES 60000
#define N_EDGES 360000
#define N_GRAPH 64
#define HID 512
#define NCLS 1000
#define BN_EPS 1e-5f
#define NS ((size_t)N_NODES * HID)
#define NB 235      // (N_NODES + 255) / 256
#define STRIPS 469  // ceil(60000/128)

typedef __bf16 bf16x8 __attribute__((ext_vector_type(8)));
typedef float f32x4 __attribute__((ext_vector_type(4)));

static __device__ __forceinline__ unsigned short f2bf(float f) {
  unsigned u = __float_as_uint(f);
  unsigned r = (u + 0x7fffu + ((u >> 16) & 1u)) >> 16;  // RNE
  return (unsigned short)r;
}
static __device__ __forceinline__ float bfLo(unsigned u) { return __uint_as_float(u << 16); }
static __device__ __forceinline__ float bfHi(unsigned u) { return __uint_as_float(u & 0xffff0000u); }
static __device__ __forceinline__ unsigned packbf(float a, float b) {
  return (unsigned)f2bf(a) | ((unsigned)f2bf(b) << 16);
}

__global__ void write_sentinel(float* out, float v) { out[0] = v; }

// fp32 -> bf16 elementwise convert (embed input), 4 elems/thread
__global__ __launch_bounds__(256) void cvt_bf16(const float* __restrict__ X,
                                                unsigned short* __restrict__ Y,
                                                long n4) {
  long i = (long)blockIdx.x * 256 + threadIdx.x;
  if (i >= n4) return;
  float4 f = *(const float4*)(X + i * 4);
  uint2 o;
  o.x = packbf(f.x, f.y);
  o.y = packbf(f.z, f.w);
  *(uint2*)(Y + i * 4) = o;
}

// ---------------------------------------------------------------------------
// Weight fp32 -> bf16 transpose: Wt[n][k] = bf16(W[k][n]).  32x32 tiles.
// ---------------------------------------------------------------------------
__global__ __launch_bounds__(256) void wtrans(const float* __restrict__ W,
                                              unsigned short* __restrict__ Wt,
                                              int K, int N) {
  __shared__ float sh[32][33];
  int kt = blockIdx.x * 32, nt = blockIdx.y * 32;
  int tx = threadIdx.x & 31, ty = threadIdx.x >> 5;  // ty 0..7
#pragma unroll
  for (int i = 0; i < 4; ++i)
    sh[ty + i * 8][tx] = W[(size_t)(kt + ty + i * 8) * N + nt + tx];
  __syncthreads();
#pragma unroll
  for (int i = 0; i < 4; ++i)
    Wt[(size_t)(nt + ty + i * 8) * K + kt + tx] = f2bf(sh[tx][ty + i * 8]);
}

// ---------------------------------------------------------------------------
// Degree / CSR build
// ---------------------------------------------------------------------------
__global__ __launch_bounds__(256) void count_deg(const int* __restrict__ dst,
                                                 int* __restrict__ deg, int E) {
  int e = blockIdx.x * 256 + threadIdx.x;
  if (e < E) atomicAdd(&deg[dst[e]], 1);
}

__global__ __launch_bounds__(256) void make_invdeg(const int* __restrict__ deg,
                                                   float* __restrict__ inv, int n) {
  int i = blockIdx.x * 256 + threadIdx.x;
  if (i < n) inv[i] = 1.0f / fmaxf((float)deg[i], 1.0f);
}

__global__ __launch_bounds__(256) void scan_part(const int* __restrict__ deg,
                                                 int* __restrict__ bsum, int n) {
  __shared__ int sh[256];
  int i = blockIdx.x * 256 + threadIdx.x;
  sh[threadIdx.x] = (i < n) ? deg[i] : 0;
  __syncthreads();
  for (int off = 128; off; off >>= 1) {
    if (threadIdx.x < off) sh[threadIdx.x] += sh[threadIdx.x + off];
    __syncthreads();
  }
  if (threadIdx.x == 0) bsum[blockIdx.x] = sh[0];
}

__global__ __launch_bounds__(256) void scan_bsums(int* __restrict__ bsum, int nb) {
  __shared__ int sh[256];
  int t = threadIdx.x;
  int v = (t < nb) ? bsum[t] : 0;
  sh[t] = v;
  __syncthreads();
  for (int off = 1; off < 256; off <<= 1) {
    int u = (t >= off) ? sh[t - off] : 0;
    __syncthreads();
    sh[t] += u;
    __syncthreads();
  }
  if (t < nb) bsum[t] = sh[t] - v;  // exclusive
}

__global__ __launch_bounds__(256) void scan_final(const int* __restrict__ deg,
                                                  const int* __restrict__ bsum,
                                                  int* __restrict__ rowptr, int n) {
  __shared__ int sh[256];
  int t = threadIdx.x;
  int i = blockIdx.x * 256 + t;
  int v = (i < n) ? deg[i] : 0;
  sh[t] = v;
  __syncthreads();
  for (int off = 1; off < 256; off <<= 1) {
    int u = (t >= off) ? sh[t - off] : 0;
    __syncthreads();
    sh[t] += u;
    __syncthreads();
  }
  if (i < n) rowptr[i + 1] = bsum[blockIdx.x] + sh[t];
  if (i == 0) rowptr[0] = 0;
}

__global__ __launch_bounds__(256) void fill_csr(const int* __restrict__ src,
                                                const int* __restrict__ dst,
                                                const int* __restrict__ rowptr,
                                                int* __restrict__ fillc,
                                                int* __restrict__ esrc, int E) {
  int e = blockIdx.x * 256 + threadIdx.x;
  if (e < E) {
    int d = dst[e];
    int pos = rowptr[d] + atomicAdd(&fillc[d], 1);
    esrc[pos] = src[e];
  }
}

// LDS-histogram batch count
__global__ __launch_bounds__(256) void bcount(const int* __restrict__ batch,
                                              float* __restrict__ bcnt, int n) {
  __shared__ int h[N_GRAPH];
  if (threadIdx.x < N_GRAPH) h[threadIdx.x] = 0;
  __syncthreads();
  int i = blockIdx.x * 256 + threadIdx.x;
  if (i < n) atomicAdd(&h[batch[i]], 1);
  __syncthreads();
  if (threadIdx.x < N_GRAPH && h[threadIdx.x])
    atomicAdd(&bcnt[threadIdx.x], (float)h[threadIdx.x]);
}

// ---------------------------------------------------------------------------
// Shared GEMM block body (m97 structure, R11-verified):
// 128x128 tile, BK=32, 4 waves; glds lane-remap staging (0 conflicts),
// LDS-bounce epilogue (coalesced uint4 stores).
// ---------------------------------------------------------------------------
#define GEMM_BODY(Xb, ldx, Wtb, ldw, bias_p, outp, KDIM)                        \
  const int wv = tid >> 6, lane = tid & 63;                                     \
  const int wm = (wv >> 1) * 64, wn = (wv & 1) * 64;                            \
  const int lm = lane & 15, quad = lane >> 4;                                   \
  const int grow = lane & 15, gseg = (lane >> 4) * 8;                           \
  f32x4 zero; zero[0] = 0.f; zero[1] = 0.f; zero[2] = 0.f; zero[3] = 0.f;       \
  f32x4 acc[4][4];                                                              \
  _Pragma("unroll") for (int i = 0; i < 4; ++i)                                 \
    _Pragma("unroll") for (int j = 0; j < 4; ++j) acc[i][j] = zero;             \
  for (int kt = 0; kt < (KDIM); kt += 32) {                                     \
    __syncthreads();                                                            \
    _Pragma("unroll") for (int r = 0; r < 2; ++r) {                             \
      int chunk = wv + r * 4;                                                   \
      int row = chunk * 16 + grow;                                              \
      const unsigned short* ga = (Xb) + (size_t)(bm + row) * (ldx) + kt + gseg; \
      const unsigned short* gb = (Wtb) + (size_t)(bn + row) * (ldw) + kt + gseg;\
      __builtin_amdgcn_global_load_lds(                                         \
          (const __attribute__((address_space(1))) unsigned int*)ga,            \
          (__attribute__((address_space(3))) unsigned int*)(As + chunk * 512),  \
          16, 0, 0);                                                            \
      __builtin_amdgcn_global_load_lds(                                         \
          (const __attribute__((address_space(1))) unsigned int*)gb,            \
          (__attribute__((address_space(3))) unsigned int*)(Bs + chunk * 512),  \
          16, 0, 0);                                                            \
    }                                                                           \
    __syncthreads();                                                            \
    bf16x8 af[4], bfr[4];                                                       \
    _Pragma("unroll") for (int i = 0; i < 4; ++i)                               \
      af[i] = *(const bf16x8*)(As + (wm / 16 + i) * 512 + lane * 8);            \
    _Pragma("unroll") for (int j = 0; j < 4; ++j)                               \
      bfr[j] = *(const bf16x8*)(Bs + (wn / 16 + j) * 512 + lane * 8);           \
    _Pragma("unroll") for (int i = 0; i < 4; ++i)                               \
      _Pragma("unroll") for (int j = 0; j < 4; ++j)                             \
        acc[i][j] = __builtin_amdgcn_mfma_f32_16x16x32_bf16(af[i], bfr[j],      \
                                                            acc[i][j], 0, 0, 0);\
  }                                                                             \
  const int qr = quad * 4;                                                      \
  const int rl = tid >> 4, seg = (tid & 15) * 8;                                \
  _Pragma("unroll") for (int p = 0; p < 2; ++p) {                               \
    __syncthreads();                                                            \
    if ((wv >> 1) == p) {                                                       \
      _Pragma("unroll") for (int j = 0; j < 4; ++j) {                           \
        int col = wn + j * 16 + lm;                                             \
        float bvv = (bias_p) ? (bias_p)[bn + col] : 0.f;                        \
        _Pragma("unroll") for (int i = 0; i < 4; ++i)                           \
          _Pragma("unroll") for (int r = 0; r < 4; ++r)                         \
            Cs[i * 16 + qr + r][col] = f2bf(acc[i][j][r] + bvv);                \
      }                                                                         \
    }                                                                           \
    __syncthreads();                                                            \
    _Pragma("unroll") for (int pass = 0; pass < 4; ++pass) {                    \
      int row = bm + p * 64 + pass * 16 + rl;                                   \
      if (row < M)                                                              \
        *(uint4*)((outp) + (size_t)row * 512 + bn + seg) =                      \
            *(const uint4*)(&Cs[pass * 16 + rl][seg]);                          \
    }                                                                           \
  }

// single-output GEMM (embed K=256, SAGE2-Yb K=512); XCD-swizzled 1-D grid
__global__ __launch_bounds__(256) void gemm_glds(
    const unsigned short* __restrict__ Xb, int ldx, int K,
    const unsigned short* __restrict__ Wt, int ldw,
    const float* __restrict__ bias,
    unsigned short* __restrict__ outB, int M) {
  __shared__ __align__(16) unsigned short As[128 * 32];
  __shared__ __align__(16) unsigned short Bs[128 * 32];
  __shared__ __align__(16) unsigned short Cs[64][136];
  const int tid = threadIdx.x;
  const int L = blockIdx.x;
  const int xcd = L & 7, li = L >> 3;
  const int strip = xcd * 59 + (li >> 2);
  if (strip >= STRIPS) return;
  const int bm = strip * 128;
  const int bn = (li & 3) * 128;
  GEMM_BODY(Xb, ldx, Wt, ldw, bias, outB, K)
}

// dual-output GEMM: cols 0..511 of W -> outA(+bias), 512..1023 -> outB.
// Used for SAGE1 (both outputs from same A; A tile fetched once per XCD).
__global__ __launch_bounds__(256) void gemm_dual(
    const unsigned short* __restrict__ Xb, int ldx,
    const unsigned short* __restrict__ Wt,  // [512][1024]
    const float* __restrict__ biasA,
    unsigned short* __restrict__ outA, unsigned short* __restrict__ outBf,
    int M) {
  __shared__ __align__(16) unsigned short As[128 * 32];
  __shared__ __align__(16) unsigned short Bs[128 * 32];
  __shared__ __align__(16) unsigned short Cs[64][136];
  const int tid = threadIdx.x;
  const int L = blockIdx.x;
  const int xcd = L & 7, li = L >> 3;
  const int strip = xcd * 59 + (li >> 3);
  if (strip >= STRIPS) return;
  const int cb = li & 7;
  const int bm = strip * 128;
  const int bn = (cb & 3) * 128;
  const unsigned short* Wtb = Wt + (cb < 4 ? 0 : 512);
  const float* bias = (cb < 4) ? biasA : nullptr;
  unsigned short* outp = (cb < 4) ? outA : outBf;
  GEMM_BODY(Xb, ldx, Wtb, 1024, bias, outp, 512)
}

// ---------------------------------------------------------------------------
// Row-strip MFMA GEMM — IN-PLACE SAFE (SAGE2 Ya), R11-proven (<87us).
// ---------------------------------------------------------------------------
__global__ __launch_bounds__(512) void gemm_strip(
    const unsigned short* __restrict__ Xb, int ldx,
    const unsigned short* __restrict__ Wt, int ldw,
    const float* __restrict__ bias,
    unsigned short* __restrict__ outB, int M) {
  __shared__ __align__(16) unsigned short As[64][40];
  const int tid = threadIdx.x;
  const int bm = blockIdx.x * 64;
  const int wv = tid >> 6, lane = tid & 63;
  const int lm = lane & 15, quad = lane >> 4, lk = quad * 8;
  const int cb = wv * 64;
  const int arow = tid >> 3, aseg = (tid & 7) * 4;

  f32x4 zero;
  zero[0] = 0.f; zero[1] = 0.f; zero[2] = 0.f; zero[3] = 0.f;
  f32x4 acc[4][4];
#pragma unroll
  for (int i = 0; i < 4; ++i)
#pragma unroll
    for (int j = 0; j < 4; ++j) acc[i][j] = zero;

  for (int kt = 0; kt < 512; kt += 32) {
    uint2 av = make_uint2(0, 0);
    int gr = bm + arow;
    if (gr < M) av = *(const uint2*)(Xb + (size_t)gr * ldx + kt + aseg);
    bf16x8 bfr[4];
#pragma unroll
    for (int j = 0; j < 4; ++j)
      bfr[j] = *(const bf16x8*)(Wt + (size_t)(cb + j * 16 + lm) * ldw + kt + lk);
    __syncthreads();
    *(uint2*)(&As[arow][aseg]) = av;
    __syncthreads();
    bf16x8 af[4];
#pragma unroll
    for (int i = 0; i < 4; ++i) af[i] = *(const bf16x8*)(&As[i * 16 + lm][lk]);
#pragma unroll
    for (int i = 0; i < 4; ++i)
#pragma unroll
      for (int j = 0; j < 4; ++j)
        acc[i][j] = __builtin_amdgcn_mfma_f32_16x16x32_bf16(af[i], bfr[j], acc[i][j], 0, 0, 0);
  }

  const int qr = quad * 4;
#pragma unroll
  for (int j = 0; j < 4; ++j) {
    int col = cb + j * 16 + lm;
    float bvv = bias ? bias[col] : 0.f;
#pragma unroll
    for (int i = 0; i < 4; ++i) {
      int rbase = bm + i * 16 + qr;
#pragma unroll
      for (int r = 0; r < 4; ++r) {
        int row = rbase + r;
        if (row < M) outB[(size_t)row * 512 + col] = f2bf(acc[i][j][r] + bvv);
      }
    }
  }
}

// ---------------------------------------------------------------------------
// Fused aggregation + L2 row-norm + BN column stats.
// Block = 64 nodes (4 waves x 16 sequential); per-wave register col-sums,
// LDS combine, 1024 global atomics/block (938 blocks).
// ---------------------------------------------------------------------------
__global__ __launch_bounds__(256) void aggr_norm_stats(
    unsigned short* __restrict__ Ya, const unsigned short* __restrict__ Yb,
    const int* __restrict__ rowptr, const int* __restrict__ esrc,
    const float* __restrict__ invdeg, float* __restrict__ sums, int M) {
  __shared__ float ps[4][1024];
  const int tid = threadIdx.x;
  const int w = tid >> 6, lane = tid & 63;
  float s[8] = {}, q[8] = {};
  const int base = blockIdx.x * 64 + w * 16;
  for (int n = 0; n < 16; ++n) {
    int d = base + n;
    if (d >= M) break;  // wave-uniform
    float acc[8] = {0.f, 0.f, 0.f, 0.f, 0.f, 0.f, 0.f, 0.f};
    int beg = rowptr[d], end = rowptr[d + 1];
    for (int e = beg; e < end; ++e) {
      int src = esrc[e];
      uint4 u = *(const uint4*)(Yb + (size_t)src * 512 + lane * 8);
      acc[0] += bfLo(u.x); acc[1] += bfHi(u.x);
      acc[2] += bfLo(u.y); acc[3] += bfHi(u.y);
      acc[4] += bfLo(u.z); acc[5] += bfHi(u.z);
      acc[6] += bfLo(u.w); acc[7] += bfHi(u.w);
    }
    float iv = invdeg[d];
    uint4 a = *(const uint4*)(Ya + (size_t)d * 512 + lane * 8);
    float r0 = bfLo(a.x) + iv * acc[0], r1 = bfHi(a.x) + iv * acc[1];
    float r2 = bfLo(a.y) + iv * acc[2], r3 = bfHi(a.y) + iv * acc[3];
    float r4 = bfLo(a.z) + iv * acc[4], r5 = bfHi(a.z) + iv * acc[5];
    float r6 = bfLo(a.w) + iv * acc[6], r7 = bfHi(a.w) + iv * acc[7];
    float ss = r0 * r0 + r1 * r1 + r2 * r2 + r3 * r3
             + r4 * r4 + r5 * r5 + r6 * r6 + r7 * r7;
#pragma unroll
    for (int o = 32; o; o >>= 1) ss += __shfl_xor(ss, o, 64);
    float inv = 1.0f / fmaxf(sqrtf(ss), 1e-12f);
    float v[8] = {r0 * inv, r1 * inv, r2 * inv, r3 * inv,
                  r4 * inv, r5 * inv, r6 * inv, r7 * inv};
#pragma unroll
    for (int k = 0; k < 8; ++k) { s[k] += v[k]; q[k] += v[k] * v[k]; }
    uint4 o4;
    o4.x = packbf(v[0], v[1]); o4.y = packbf(v[2], v[3]);
    o4.z = packbf(v[4], v[5]); o4.w = packbf(v[6], v[7]);
    *(uint4*)(Ya + (size_t)d * 512 + lane * 8) = o4;
  }
#pragma unroll
  for (int k = 0; k < 8; ++k) {
    ps[w][lane * 8 + k] = s[k];
    ps[w][512 + lane * 8 + k] = q[k];
  }
  __syncthreads();
  int c4 = tid * 4;
#pragma unroll
  for (int j = 0; j < 4; ++j) {
    float tot = ps[0][c4 + j] + ps[1][c4 + j] + ps[2][c4 + j] + ps[3][c4 + j];
    atomicAdd(&sums[c4 + j], tot);
  }
}

// BN apply + ReLU (+ optional residual); bf16 in/out, 2 cols per thread.
__global__ __launch_bounds__(256) void bn_apply(const unsigned short* __restrict__ U,
                                                unsigned short* __restrict__ H,
                                                const float* __restrict__ sums,
                                                const float* __restrict__ g,
                                                const float* __restrict__ be,
                                                int M, int residual) {
  size_t i2 = (size_t)blockIdx.x * 256 + threadIdx.x;
  if (i2 >= NS / 2) return;
  int c = ((int)(i2 & 255)) * 2;
  float invM = 1.0f / (float)M;
  float m0 = sums[c] * invM, m1 = sums[c + 1] * invM;
  float v0 = sums[512 + c] * invM - m0 * m0;
  float v1 = sums[512 + c + 1] * invM - m1 * m1;
  float k0 = rsqrtf(v0 + BN_EPS) * g[c], k1 = rsqrtf(v1 + BN_EPS) * g[c + 1];
  unsigned u = ((const unsigned*)U)[i2];
  float x0 = fmaxf((bfLo(u) - m0) * k0 + be[c], 0.f);
  float x1 = fmaxf((bfHi(u) - m1) * k1 + be[c + 1], 0.f);
  if (residual) {
    unsigned hv = ((const unsigned*)H)[i2];
    x0 += bfLo(hv);
    x1 += bfHi(hv);
  }
  ((unsigned*)H)[i2] = packbf(x0, x1);
}

// ---------------------------------------------------------------------------
// Attention pool, sorted-batch segmented, 64 nodes/block (938 blocks).
// ---------------------------------------------------------------------------
#define NPB 64
__global__ __launch_bounds__(256) void att_pool2(const unsigned short* __restrict__ H,
                                                 const int* __restrict__ batch,
                                                 const float* __restrict__ Watt,
                                                 float* __restrict__ hg, int M) {
  __shared__ float fsh[NPB];
  __shared__ int bsh[NPB];
  const int tid = threadIdx.x;
  const int base = blockIdx.x * NPB;
  if (tid < NPB) bsh[tid] = (base + tid < M) ? batch[base + tid] : -1;
  const int wv = tid >> 6, lane = tid & 63;
  float4 wa0 = *(const float4*)(Watt + lane * 8);
  float4 wa1 = *(const float4*)(Watt + lane * 8 + 4);
  __syncthreads();
  for (int i = wv; i < NPB; i += 4) {
    int node = base + i;
    float dot = 0.f;
    if (node < M) {
      uint4 u = *(const uint4*)(H + (size_t)node * 512 + lane * 8);
      dot = bfLo(u.x) * wa0.x + bfHi(u.x) * wa0.y
          + bfLo(u.y) * wa0.z + bfHi(u.y) * wa0.w
          + bfLo(u.z) * wa1.x + bfHi(u.z) * wa1.y
          + bfLo(u.w) * wa1.z + bfHi(u.w) * wa1.w;
    }
#pragma unroll
    for (int o = 32; o; o >>= 1) dot += __shfl_xor(dot, o, 64);
    if (lane == 0) fsh[i] = 0.5f * (1.0f + 1.0f / (1.0f + expf(-dot)));
  }
  __syncthreads();
  float a0 = 0.f, a1 = 0.f;
  int cur = bsh[0];
  for (int i = 0; i < NPB; ++i) {
    int node = base + i;
    if (node >= M) break;
    int b = bsh[i];
    if (b != cur) {
      atomicAdd(&hg[(size_t)cur * 512 + tid * 2], a0);
      atomicAdd(&hg[(size_t)cur * 512 + tid * 2 + 1], a1);
      a0 = a1 = 0.f;
      cur = b;
    }
    unsigned u = *(const unsigned*)(H + (size_t)node * 512 + tid * 2);
    float f = fsh[i];
    a0 += bfLo(u) * f;
    a1 += bfHi(u) * f;
  }
  if (cur >= 0) {
    atomicAdd(&hg[(size_t)cur * 512 + tid * 2], a0);
    atomicAdd(&hg[(size_t)cur * 512 + tid * 2 + 1], a1);
  }
}

// ---------------------------------------------------------------------------
// Readout: out[g, n] = (hg[g]/bcnt[g]) . Wread[:, n]
// ---------------------------------------------------------------------------
__global__ __launch_bounds__(256) void readout(const float* __restrict__ hg,
                                               const float* __restrict__ bcnt,
                                               const float* __restrict__ Wr,
                                               float* __restrict__ out) {
  __shared__ float sh[HID];
  int g = blockIdx.x;
  int n = blockIdx.y * 256 + threadIdx.x;
  float inv = 1.0f / fmaxf(bcnt[g], 1.0f);
  for (int k = threadIdx.x; k < HID; k += 256) sh[k] = hg[(size_t)g * HID + k] * inv;
  __syncthreads();
  if (n < NCLS) {
    float acc = 0.f;
    for (int k = 0; k < HID; ++k) acc += sh[k] * Wr[(size_t)k * NCLS + n];
    out[(size_t)g * NCLS + n] = acc;
  }
}

// ---------------------------------------------------------------------------
extern "C" void kernel_launch(void* const* d_in, const int* in_sizes, int n_in,
                              void* d_out, int out_size, void* d_ws, size_t ws_size,
                              hipStream_t stream) {
  const float* x       = (const float*)d_in[0];
  const int*   ei      = (const int*)d_in[1];
  const int*   batch   = (const int*)d_in[2];
  const float* W_embed = (const float*)d_in[3];
  const float* W1      = (const float*)d_in[4];
  const float* b1      = (const float*)d_in[5];
  const float* g1      = (const float*)d_in[6];
  const float* be1     = (const float*)d_in[7];
  const float* W2      = (const float*)d_in[8];
  const float* b2      = (const float*)d_in[9];
  const float* g2      = (const float*)d_in[10];
  const float* be2     = (const float*)d_in[11];
  const float* Watt    = (const float*)d_in[12];
  const float* Wread   = (const float*)d_in[13];
  float* out = (float*)d_out;

  const int* srcIdx = ei;
  const int* dstIdx = ei + N_EDGES;

  char* p = (char*)d_ws;
  unsigned short* B0 = (unsigned short*)p; p += NS * 2;   // h (residual)
  unsigned short* B1 = (unsigned short*)p; p += NS * 2;   // Ya / T / x_bf16
  unsigned short* B2 = (unsigned short*)p; p += NS * 2;   // Yb
  unsigned short* WtE = (unsigned short*)p; p += (size_t)512 * 256 * 2;
  unsigned short* Wt1 = (unsigned short*)p; p += (size_t)3 * 512 * 1024 * 2;
  unsigned short* Wt2 = (unsigned short*)p; p += (size_t)3 * 512 * 1024 * 2;
  float* hg     = (float*)p; p += (size_t)N_GRAPH * HID * 4;
  float* sums   = (float*)p; p += 1024 * 4;
  float* invdeg = (float*)p; p += (size_t)N_NODES * 4;
  float* bcnt   = (float*)p; p += 256;
  int* deg      = (int*)p;   p += (size_t)N_NODES * 4;
  int* fillc    = (int*)p;   p += (size_t)N_NODES * 4;
  int* esrc     = (int*)p;   p += (size_t)N_EDGES * 4;
  int* rowptr   = (int*)p;   p += (size_t)(N_NODES + 1) * 4;
  int* bsum     = (int*)p;   p += (size_t)NB * 4;
  size_t need = (size_t)(p - (char*)d_ws);
  if (ws_size < need) {
    write_sentinel<<<1, 1, 0, stream>>>(out, (float)need);
    return;
  }

  // ---- weight prep (fp32 -> bf16, transposed [N][K])
  wtrans<<<dim3(8, 16), 256, 0, stream>>>(W_embed, WtE, 256, 512);
  for (int l = 0; l < 3; ++l) {
    wtrans<<<dim3(32, 16), 256, 0, stream>>>(W1 + (size_t)l * 1024 * 512,
                                             Wt1 + (size_t)l * 512 * 1024, 1024, 512);
    wtrans<<<dim3(32, 16), 256, 0, stream>>>(W2 + (size_t)l * 1024 * 512,
                                             Wt2 + (size_t)l * 512 * 1024, 1024, 512);
  }

  // ---- CSR build (parallel scan)
  hipMemsetAsync(deg, 0, N_NODES * sizeof(int), stream);
  hipMemsetAsync(fillc, 0, N_NODES * sizeof(int), stream);
  count_deg<<<(N_EDGES + 255) / 256, 256, 0, stream>>>(dstIdx, deg, N_EDGES);
  make_invdeg<<<(N_NODES + 255) / 256, 256, 0, stream>>>(deg, invdeg, N_NODES);
  scan_part<<<NB, 256, 0, stream>>>(deg, bsum, N_NODES);
  scan_bsums<<<1, 256, 0, stream>>>(bsum, NB);
  scan_final<<<NB, 256, 0, stream>>>(deg, bsum, rowptr, N_NODES);
  fill_csr<<<(N_EDGES + 255) / 256, 256, 0, stream>>>(srcIdx, dstIdx, rowptr, fillc,
                                                      esrc, N_EDGES);

  const int g1grid = 8 * 59 * 4;  // single-output GEMM grid (1888)
  const int g2grid = 8 * 59 * 8;  // dual-output GEMM grid (3776)
  const int sgrid  = (N_NODES + 63) / 64;
  const int agrid  = (N_NODES + 63) / 64;   // aggr_norm_stats: 64 nodes/block
  const int egrid  = (int)((NS / 2 + 255) / 256);

  // ---- embed: x -> bf16 (B1), then h = x @ W_embed -> B0
  cvt_bf16<<<(int)(((size_t)N_NODES * 64 + 255) / 256), 256, 0, stream>>>(
      x, B1, (long)N_NODES * 64);
  gemm_glds<<<g1grid, 256, 0, stream>>>(B1, 256, 256, WtE, 256, nullptr, B0, N_NODES);

  for (int l = 0; l < 3; ++l) {
    const unsigned short* Wt1l = Wt1 + (size_t)l * 512 * 1024;
    const unsigned short* Wt2l = Wt2 + (size_t)l * 512 * 1024;
    // ---- SAGE 1: B1 = Ya+bias, B2 = Yb (one fused launch), then aggr+stats
    hipMemsetAsync(sums, 0, 1024 * sizeof(float), stream);
    gemm_dual<<<g2grid, 256, 0, stream>>>(B0, 512, Wt1l, b1 + l * 512, B1, B2, N_NODES);
    aggr_norm_stats<<<agrid, 256, 0, stream>>>(B1, B2, rowptr, esrc, invdeg,
                                               sums, N_NODES);
    bn_apply<<<egrid, 256, 0, stream>>>(B1, B1, sums, g1 + l * 512,
                                        be1 + l * 512, N_NODES, 0);
    // ---- SAGE 2 + residual
    hipMemsetAsync(sums, 0, 1024 * sizeof(float), stream);
    gemm_glds<<<g1grid, 256, 0, stream>>>(B1, 512, 512, Wt2l + 512, 1024,
                                          nullptr, B2, N_NODES);         // Yb
    gemm_strip<<<sgrid, 512, 0, stream>>>(B1, 512, Wt2l, 1024,
                                          b2 + l * 512, B1, N_NODES);    // Ya in-place
    aggr_norm_stats<<<agrid, 256, 0, stream>>>(B1, B2, rowptr, esrc, invdeg,
                                               sums, N_NODES);
    bn_apply<<<egrid, 256, 0, stream>>>(B1, B0, sums, g2 + l * 512,
                                        be2 + l * 512, N_NODES, 1);
  }

  // ---- pooling + readout
  hipMemsetAsync(hg, 0, (size_t)N_GRAPH * HID * sizeof(float), stream);
  hipMemsetAsync(bcnt, 0, N_GRAPH * sizeof(float), stream);
  bcount<<<NB, 256, 0, stream>>>(batch, bcnt, N_NODES);
  att_pool2<<<(N_NODES + NPB - 1) / NPB, 256, 0, stream>>>(B0, batch, Watt, hg, N_NODES);
  readout<<<dim3(N_GRAPH, 4), 256, 0, stream>>>(hg, bcnt, Wread, out);
}

// Round 13
// 2083.563 us; speedup vs baseline: 1.1617x; 1.1617x over previous
//
#include <hip/hip_runtime.h>
#include <math.h>

#define N_NODES 60000
#define N_EDGES 360000
#define N_GRAPH 64
#define HID 512
#define NCLS 1000
#define BN_EPS 1e-5f
#define NS ((size_t)N_NODES * HID)
#define NB 235      // (N_NODES + 255) / 256
#define STRIPS 469  // ceil(60000/128)

typedef __bf16 bf16x8 __attribute__((ext_vector_type(8)));
typedef float f32x4 __attribute__((ext_vector_type(4)));

static __device__ __forceinline__ unsigned short f2bf(float f) {
  unsigned u = __float_as_uint(f);
  unsigned r = (u + 0x7fffu + ((u >> 16) & 1u)) >> 16;  // RNE
  return (unsigned short)r;
}
static __device__ __forceinline__ float bfLo(unsigned u) { return __uint_as_float(u << 16); }
static __device__ __forceinline__ float bfHi(unsigned u) { return __uint_as_float(u & 0xffff0000u); }
static __device__ __forceinline__ unsigned packbf(float a, float b) {
  return (unsigned)f2bf(a) | ((unsigned)f2bf(b) << 16);
}

__global__ void write_sentinel(float* out, float v) { out[0] = v; }

// fp32 -> bf16 elementwise convert (embed input), 4 elems/thread
__global__ __launch_bounds__(256) void cvt_bf16(const float* __restrict__ X,
                                                unsigned short* __restrict__ Y,
                                                long n4) {
  long i = (long)blockIdx.x * 256 + threadIdx.x;
  if (i >= n4) return;
  float4 f = *(const float4*)(X + i * 4);
  uint2 o;
  o.x = packbf(f.x, f.y);
  o.y = packbf(f.z, f.w);
  *(uint2*)(Y + i * 4) = o;
}

// ---------------------------------------------------------------------------
// Weight fp32 -> bf16 transpose: Wt[n][k] = bf16(W[k][n]).  32x32 tiles.
// ---------------------------------------------------------------------------
__global__ __launch_bounds__(256) void wtrans(const float* __restrict__ W,
                                              unsigned short* __restrict__ Wt,
                                              int K, int N) {
  __shared__ float sh[32][33];
  int kt = blockIdx.x * 32, nt = blockIdx.y * 32;
  int tx = threadIdx.x & 31, ty = threadIdx.x >> 5;  // ty 0..7
#pragma unroll
  for (int i = 0; i < 4; ++i)
    sh[ty + i * 8][tx] = W[(size_t)(kt + ty + i * 8) * N + nt + tx];
  __syncthreads();
#pragma unroll
  for (int i = 0; i < 4; ++i)
    Wt[(size_t)(nt + ty + i * 8) * K + kt + tx] = f2bf(sh[tx][ty + i * 8]);
}

// ---------------------------------------------------------------------------
// Degree / CSR build
// ---------------------------------------------------------------------------
__global__ __launch_bounds__(256) void count_deg(const int* __restrict__ dst,
                                                 int* __restrict__ deg, int E) {
  int e = blockIdx.x * 256 + threadIdx.x;
  if (e < E) atomicAdd(&deg[dst[e]], 1);
}

__global__ __launch_bounds__(256) void make_invdeg(const int* __restrict__ deg,
                                                   float* __restrict__ inv, int n) {
  int i = blockIdx.x * 256 + threadIdx.x;
  if (i < n) inv[i] = 1.0f / fmaxf((float)deg[i], 1.0f);
}

__global__ __launch_bounds__(256) void scan_part(const int* __restrict__ deg,
                                                 int* __restrict__ bsum, int n) {
  __shared__ int sh[256];
  int i = blockIdx.x * 256 + threadIdx.x;
  sh[threadIdx.x] = (i < n) ? deg[i] : 0;
  __syncthreads();
  for (int off = 128; off; off >>= 1) {
    if (threadIdx.x < off) sh[threadIdx.x] += sh[threadIdx.x + off];
    __syncthreads();
  }
  if (threadIdx.x == 0) bsum[blockIdx.x] = sh[0];
}

__global__ __launch_bounds__(256) void scan_bsums(int* __restrict__ bsum, int nb) {
  __shared__ int sh[256];
  int t = threadIdx.x;
  int v = (t < nb) ? bsum[t] : 0;
  sh[t] = v;
  __syncthreads();
  for (int off = 1; off < 256; off <<= 1) {
    int u = (t >= off) ? sh[t - off] : 0;
    __syncthreads();
    sh[t] += u;
    __syncthreads();
  }
  if (t < nb) bsum[t] = sh[t] - v;  // exclusive
}

__global__ __launch_bounds__(256) void scan_final(const int* __restrict__ deg,
                                                  const int* __restrict__ bsum,
                                                  int* __restrict__ rowptr, int n) {
  __shared__ int sh[256];
  int t = threadIdx.x;
  int i = blockIdx.x * 256 + t;
  int v = (i < n) ? deg[i] : 0;
  sh[t] = v;
  __syncthreads();
  for (int off = 1; off < 256; off <<= 1) {
    int u = (t >= off) ? sh[t - off] : 0;
    __syncthreads();
    sh[t] += u;
    __syncthreads();
  }
  if (i < n) rowptr[i + 1] = bsum[blockIdx.x] + sh[t];
  if (i == 0) rowptr[0] = 0;
}

__global__ __launch_bounds__(256) void fill_csr(const int* __restrict__ src,
                                                const int* __restrict__ dst,
                                                const int* __restrict__ rowptr,
                                                int* __restrict__ fillc,
                                                int* __restrict__ esrc, int E) {
  int e = blockIdx.x * 256 + threadIdx.x;
  if (e < E) {
    int d = dst[e];
    int pos = rowptr[d] + atomicAdd(&fillc[d], 1);
    esrc[pos] = src[e];
  }
}

// LDS-histogram batch count
__global__ __launch_bounds__(256) void bcount(const int* __restrict__ batch,
                                              float* __restrict__ bcnt, int n) {
  __shared__ int h[N_GRAPH];
  if (threadIdx.x < N_GRAPH) h[threadIdx.x] = 0;
  __syncthreads();
  int i = blockIdx.x * 256 + threadIdx.x;
  if (i < n) atomicAdd(&h[batch[i]], 1);
  __syncthreads();
  if (threadIdx.x < N_GRAPH && h[threadIdx.x])
    atomicAdd(&bcnt[threadIdx.x], (float)h[threadIdx.x]);
}

// ---------------------------------------------------------------------------
// Shared GEMM block body (m97 structure, R11-verified):
// 128x128 tile, BK=32, 4 waves; glds lane-remap staging (0 conflicts),
// LDS-bounce epilogue (coalesced uint4 stores).
// ---------------------------------------------------------------------------
#define GEMM_BODY(Xb, ldx, Wtb, ldw, bias_p, outp, KDIM)                        \
  const int wv = tid >> 6, lane = tid & 63;                                     \
  const int wm = (wv >> 1) * 64, wn = (wv & 1) * 64;                            \
  const int lm = lane & 15, quad = lane >> 4;                                   \
  const int grow = lane & 15, gseg = (lane >> 4) * 8;                           \
  f32x4 zero; zero[0] = 0.f; zero[1] = 0.f; zero[2] = 0.f; zero[3] = 0.f;       \
  f32x4 acc[4][4];                                                              \
  _Pragma("unroll") for (int i = 0; i < 4; ++i)                                 \
    _Pragma("unroll") for (int j = 0; j < 4; ++j) acc[i][j] = zero;             \
  for (int kt = 0; kt < (KDIM); kt += 32) {                                     \
    __syncthreads();                                                            \
    _Pragma("unroll") for (int r = 0; r < 2; ++r) {                             \
      int chunk = wv + r * 4;                                                   \
      int row = chunk * 16 + grow;                                              \
      const unsigned short* ga = (Xb) + (size_t)(bm + row) * (ldx) + kt + gseg; \
      const unsigned short* gb = (Wtb) + (size_t)(bn + row) * (ldw) + kt + gseg;\
      __builtin_amdgcn_global_load_lds(                                         \
          (const __attribute__((address_space(1))) unsigned int*)ga,            \
          (__attribute__((address_space(3))) unsigned int*)(As + chunk * 512),  \
          16, 0, 0);                                                            \
      __builtin_amdgcn_global_load_lds(                                         \
          (const __attribute__((address_space(1))) unsigned int*)gb,            \
          (__attribute__((address_space(3))) unsigned int*)(Bs + chunk * 512),  \
          16, 0, 0);                                                            \
    }                                                                           \
    __syncthreads();                                                            \
    bf16x8 af[4], bfr[4];                                                       \
    _Pragma("unroll") for (int i = 0; i < 4; ++i)                               \
      af[i] = *(const bf16x8*)(As + (wm / 16 + i) * 512 + lane * 8);            \
    _Pragma("unroll") for (int j = 0; j < 4; ++j)                               \
      bfr[j] = *(const bf16x8*)(Bs + (wn / 16 + j) * 512 + lane * 8);           \
    _Pragma("unroll") for (int i = 0; i < 4; ++i)                               \
      _Pragma("unroll") for (int j = 0; j < 4; ++j)                             \
        acc[i][j] = __builtin_amdgcn_mfma_f32_16x16x32_bf16(af[i], bfr[j],      \
                                                            acc[i][j], 0, 0, 0);\
  }                                                                             \
  const int qr = quad * 4;                                                      \
  const int rl = tid >> 4, seg = (tid & 15) * 8;                                \
  _Pragma("unroll") for (int p = 0; p < 2; ++p) {                               \
    __syncthreads();                                                            \
    if ((wv >> 1) == p) {                                                       \
      _Pragma("unroll") for (int j = 0; j < 4; ++j) {                           \
        int col = wn + j * 16 + lm;                                             \
        float bvv = (bias_p) ? (bias_p)[bn + col] : 0.f;                        \
        _Pragma("unroll") for (int i = 0; i < 4; ++i)                           \
          _Pragma("unroll") for (int r = 0; r < 4; ++r)                         \
            Cs[i * 16 + qr + r][col] = f2bf(acc[i][j][r] + bvv);                \
      }                                                                         \
    }                                                                           \
    __syncthreads();                                                            \
    _Pragma("unroll") for (int pass = 0; pass < 4; ++pass) {                    \
      int row = bm + p * 64 + pass * 16 + rl;                                   \
      if (row < M)                                                              \
        *(uint4*)((outp) + (size_t)row * 512 + bn + seg) =                      \
            *(const uint4*)(&Cs[pass * 16 + rl][seg]);                          \
    }                                                                           \
  }

// single-output GEMM (embed K=256, SAGE2-Yb K=512); XCD-swizzled 1-D grid
__global__ __launch_bounds__(256) void gemm_glds(
    const unsigned short* __restrict__ Xb, int ldx, int K,
    const unsigned short* __restrict__ Wt, int ldw,
    const float* __restrict__ bias,
    unsigned short* __restrict__ outB, int M) {
  __shared__ __align__(16) unsigned short As[128 * 32];
  __shared__ __align__(16) unsigned short Bs[128 * 32];
  __shared__ __align__(16) unsigned short Cs[64][136];
  const int tid = threadIdx.x;
  const int L = blockIdx.x;
  const int xcd = L & 7, li = L >> 3;
  const int strip = xcd * 59 + (li >> 2);
  if (strip >= STRIPS) return;
  const int bm = strip * 128;
  const int bn = (li & 3) * 128;
  GEMM_BODY(Xb, ldx, Wt, ldw, bias, outB, K)
}

// dual-output GEMM: cols 0..511 of W -> outA(+bias), 512..1023 -> outB.
__global__ __launch_bounds__(256) void gemm_dual(
    const unsigned short* __restrict__ Xb, int ldx,
    const unsigned short* __restrict__ Wt,  // [512][1024]
    const float* __restrict__ biasA,
    unsigned short* __restrict__ outA, unsigned short* __restrict__ outBf,
    int M) {
  __shared__ __align__(16) unsigned short As[128 * 32];
  __shared__ __align__(16) unsigned short Bs[128 * 32];
  __shared__ __align__(16) unsigned short Cs[64][136];
  const int tid = threadIdx.x;
  const int L = blockIdx.x;
  const int xcd = L & 7, li = L >> 3;
  const int strip = xcd * 59 + (li >> 3);
  if (strip >= STRIPS) return;
  const int cb = li & 7;
  const int bm = strip * 128;
  const int bn = (cb & 3) * 128;
  const unsigned short* Wtb = Wt + (cb < 4 ? 0 : 512);
  const float* bias = (cb < 4) ? biasA : nullptr;
  unsigned short* outp = (cb < 4) ? outA : outBf;
  GEMM_BODY(Xb, ldx, Wtb, 1024, bias, outp, 512)
}

// ---------------------------------------------------------------------------
// Row-strip MFMA GEMM — IN-PLACE SAFE (SAGE2 Ya), R11-proven (<87us).
// ---------------------------------------------------------------------------
__global__ __launch_bounds__(512) void gemm_strip(
    const unsigned short* __restrict__ Xb, int ldx,
    const unsigned short* __restrict__ Wt, int ldw,
    const float* __restrict__ bias,
    unsigned short* __restrict__ outB, int M) {
  __shared__ __align__(16) unsigned short As[64][40];
  const int tid = threadIdx.x;
  const int bm = blockIdx.x * 64;
  const int wv = tid >> 6, lane = tid & 63;
  const int lm = lane & 15, quad = lane >> 4, lk = quad * 8;
  const int cb = wv * 64;
  const int arow = tid >> 3, aseg = (tid & 7) * 4;

  f32x4 zero;
  zero[0] = 0.f; zero[1] = 0.f; zero[2] = 0.f; zero[3] = 0.f;
  f32x4 acc[4][4];
#pragma unroll
  for (int i = 0; i < 4; ++i)
#pragma unroll
    for (int j = 0; j < 4; ++j) acc[i][j] = zero;

  for (int kt = 0; kt < 512; kt += 32) {
    uint2 av = make_uint2(0, 0);
    int gr = bm + arow;
    if (gr < M) av = *(const uint2*)(Xb + (size_t)gr * ldx + kt + aseg);
    bf16x8 bfr[4];
#pragma unroll
    for (int j = 0; j < 4; ++j)
      bfr[j] = *(const bf16x8*)(Wt + (size_t)(cb + j * 16 + lm) * ldw + kt + lk);
    __syncthreads();
    *(uint2*)(&As[arow][aseg]) = av;
    __syncthreads();
    bf16x8 af[4];
#pragma unroll
    for (int i = 0; i < 4; ++i) af[i] = *(const bf16x8*)(&As[i * 16 + lm][lk]);
#pragma unroll
    for (int i = 0; i < 4; ++i)
#pragma unroll
      for (int j = 0; j < 4; ++j)
        acc[i][j] = __builtin_amdgcn_mfma_f32_16x16x32_bf16(af[i], bfr[j], acc[i][j], 0, 0, 0);
  }

  const int qr = quad * 4;
#pragma unroll
  for (int j = 0; j < 4; ++j) {
    int col = cb + j * 16 + lm;
    float bvv = bias ? bias[col] : 0.f;
#pragma unroll
    for (int i = 0; i < 4; ++i) {
      int rbase = bm + i * 16 + qr;
#pragma unroll
      for (int r = 0; r < 4; ++r) {
        int row = rbase + r;
        if (row < M) outB[(size_t)row * 512 + col] = f2bf(acc[i][j][r] + bvv);
      }
    }
  }
}

// ---------------------------------------------------------------------------
// Fused aggregation + L2 row-norm (ONE WAVE PER NODE — R11-proven; the R12
// 16-nodes/wave fusion collapsed parallelism 16x and regressed 60->171us).
// ---------------------------------------------------------------------------
__global__ __launch_bounds__(256) void aggr_norm(
    unsigned short* __restrict__ Ya, const unsigned short* __restrict__ Yb,
    const int* __restrict__ rowptr, const int* __restrict__ esrc,
    const float* __restrict__ invdeg, int M) {
  int d = blockIdx.x * 4 + (threadIdx.x >> 6);
  int lane = threadIdx.x & 63;
  if (d >= M) return;
  float acc[8] = {0.f, 0.f, 0.f, 0.f, 0.f, 0.f, 0.f, 0.f};
  int beg = rowptr[d], end = rowptr[d + 1];
  for (int e = beg; e < end; ++e) {
    int s = esrc[e];
    uint4 u = *(const uint4*)(Yb + (size_t)s * 512 + lane * 8);
    acc[0] += bfLo(u.x); acc[1] += bfHi(u.x);
    acc[2] += bfLo(u.y); acc[3] += bfHi(u.y);
    acc[4] += bfLo(u.z); acc[5] += bfHi(u.z);
    acc[6] += bfLo(u.w); acc[7] += bfHi(u.w);
  }
  float iv = invdeg[d];
  uint4 a = *(const uint4*)(Ya + (size_t)d * 512 + lane * 8);
  float r0 = bfLo(a.x) + iv * acc[0], r1 = bfHi(a.x) + iv * acc[1];
  float r2 = bfLo(a.y) + iv * acc[2], r3 = bfHi(a.y) + iv * acc[3];
  float r4 = bfLo(a.z) + iv * acc[4], r5 = bfHi(a.z) + iv * acc[5];
  float r6 = bfLo(a.w) + iv * acc[6], r7 = bfHi(a.w) + iv * acc[7];
  float ss = r0 * r0 + r1 * r1 + r2 * r2 + r3 * r3
           + r4 * r4 + r5 * r5 + r6 * r6 + r7 * r7;
#pragma unroll
  for (int o = 32; o; o >>= 1) ss += __shfl_xor(ss, o, 64);
  float inv = 1.0f / fmaxf(sqrtf(ss), 1e-12f);
  uint4 o4;
  o4.x = packbf(r0 * inv, r1 * inv);
  o4.y = packbf(r2 * inv, r3 * inv);
  o4.z = packbf(r4 * inv, r5 * inv);
  o4.w = packbf(r6 * inv, r7 * inv);
  *(uint4*)(Ya + (size_t)d * 512 + lane * 8) = o4;
}

// ---------------------------------------------------------------------------
// BN stats over bf16: sums[0..511]=sum, sums[512..1023]=sumsq
// ---------------------------------------------------------------------------
__global__ __launch_bounds__(256) void bn_stats(const unsigned short* __restrict__ T,
                                                int M, float* __restrict__ sums) {
  const int t = threadIdx.x;
  int r0 = blockIdx.x * 128;
  int rend = min(r0 + 128, M);
  float s0 = 0.f, q0 = 0.f, s1 = 0.f, q1 = 0.f;
  for (int r = r0; r < rend; ++r) {
    float a = __uint_as_float((unsigned)T[(size_t)r * 512 + t] << 16);
    float b = __uint_as_float((unsigned)T[(size_t)r * 512 + t + 256] << 16);
    s0 += a; q0 += a * a; s1 += b; q1 += b * b;
  }
  atomicAdd(&sums[t], s0);
  atomicAdd(&sums[t + 256], s1);
  atomicAdd(&sums[512 + t], q0);
  atomicAdd(&sums[512 + t + 256], q1);
}

// BN apply + ReLU (+ optional residual); bf16 in/out, 2 cols per thread.
__global__ __launch_bounds__(256) void bn_apply(const unsigned short* __restrict__ U,
                                                unsigned short* __restrict__ H,
                                                const float* __restrict__ sums,
                                                const float* __restrict__ g,
                                                const float* __restrict__ be,
                                                int M, int residual) {
  size_t i2 = (size_t)blockIdx.x * 256 + threadIdx.x;
  if (i2 >= NS / 2) return;
  int c = ((int)(i2 & 255)) * 2;
  float invM = 1.0f / (float)M;
  float m0 = sums[c] * invM, m1 = sums[c + 1] * invM;
  float v0 = sums[512 + c] * invM - m0 * m0;
  float v1 = sums[512 + c + 1] * invM - m1 * m1;
  float k0 = rsqrtf(v0 + BN_EPS) * g[c], k1 = rsqrtf(v1 + BN_EPS) * g[c + 1];
  unsigned u = ((const unsigned*)U)[i2];
  float x0 = fmaxf((bfLo(u) - m0) * k0 + be[c], 0.f);
  float x1 = fmaxf((bfHi(u) - m1) * k1 + be[c + 1], 0.f);
  if (residual) {
    unsigned hv = ((const unsigned*)H)[i2];
    x0 += bfLo(hv);
    x1 += bfHi(hv);
  }
  ((unsigned*)H)[i2] = packbf(x0, x1);
}

// ---------------------------------------------------------------------------
// Attention pool, sorted-batch segmented, 64 nodes/block (938 blocks).
// ---------------------------------------------------------------------------
#define NPB 64
__global__ __launch_bounds__(256) void att_pool2(const unsigned short* __restrict__ H,
                                                 const int* __restrict__ batch,
                                                 const float* __restrict__ Watt,
                                                 float* __restrict__ hg, int M) {
  __shared__ float fsh[NPB];
  __shared__ int bsh[NPB];
  const int tid = threadIdx.x;
  const int base = blockIdx.x * NPB;
  if (tid < NPB) bsh[tid] = (base + tid < M) ? batch[base + tid] : -1;
  const int wv = tid >> 6, lane = tid & 63;
  float4 wa0 = *(const float4*)(Watt + lane * 8);
  float4 wa1 = *(const float4*)(Watt + lane * 8 + 4);
  __syncthreads();
  for (int i = wv; i < NPB; i += 4) {
    int node = base + i;
    float dot = 0.f;
    if (node < M) {
      uint4 u = *(const uint4*)(H + (size_t)node * 512 + lane * 8);
      dot = bfLo(u.x) * wa0.x + bfHi(u.x) * wa0.y
          + bfLo(u.y) * wa0.z + bfHi(u.y) * wa0.w
          + bfLo(u.z) * wa1.x + bfHi(u.z) * wa1.y
          + bfLo(u.w) * wa1.z + bfHi(u.w) * wa1.w;
    }
#pragma unroll
    for (int o = 32; o; o >>= 1) dot += __shfl_xor(dot, o, 64);
    if (lane == 0) fsh[i] = 0.5f * (1.0f + 1.0f / (1.0f + expf(-dot)));
  }
  __syncthreads();
  float a0 = 0.f, a1 = 0.f;
  int cur = bsh[0];
  for (int i = 0; i < NPB; ++i) {
    int node = base + i;
    if (node >= M) break;
    int b = bsh[i];
    if (b != cur) {
      atomicAdd(&hg[(size_t)cur * 512 + tid * 2], a0);
      atomicAdd(&hg[(size_t)cur * 512 + tid * 2 + 1], a1);
      a0 = a1 = 0.f;
      cur = b;
    }
    unsigned u = *(const unsigned*)(H + (size_t)node * 512 + tid * 2);
    float f = fsh[i];
    a0 += bfLo(u) * f;
    a1 += bfHi(u) * f;
  }
  if (cur >= 0) {
    atomicAdd(&hg[(size_t)cur * 512 + tid * 2], a0);
    atomicAdd(&hg[(size_t)cur * 512 + tid * 2 + 1], a1);
  }
}

// ---------------------------------------------------------------------------
// Readout: out[g, n] = (hg[g]/bcnt[g]) . Wread[:, n]
// ---------------------------------------------------------------------------
__global__ __launch_bounds__(256) void readout(const float* __restrict__ hg,
                                               const float* __restrict__ bcnt,
                                               const float* __restrict__ Wr,
                                               float* __restrict__ out) {
  __shared__ float sh[HID];
  int g = blockIdx.x;
  int n = blockIdx.y * 256 + threadIdx.x;
  float inv = 1.0f / fmaxf(bcnt[g], 1.0f);
  for (int k = threadIdx.x; k < HID; k += 256) sh[k] = hg[(size_t)g * HID + k] * inv;
  __syncthreads();
  if (n < NCLS) {
    float acc = 0.f;
    for (int k = 0; k < HID; ++k) acc += sh[k] * Wr[(size_t)k * NCLS + n];
    out[(size_t)g * NCLS + n] = acc;
  }
}

// ---------------------------------------------------------------------------
extern "C" void kernel_launch(void* const* d_in, const int* in_sizes, int n_in,
                              void* d_out, int out_size, void* d_ws, size_t ws_size,
                              hipStream_t stream) {
  const float* x       = (const float*)d_in[0];
  const int*   ei      = (const int*)d_in[1];
  const int*   batch   = (const int*)d_in[2];
  const float* W_embed = (const float*)d_in[3];
  const float* W1      = (const float*)d_in[4];
  const float* b1      = (const float*)d_in[5];
  const float* g1      = (const float*)d_in[6];
  const float* be1     = (const float*)d_in[7];
  const float* W2      = (const float*)d_in[8];
  const float* b2      = (const float*)d_in[9];
  const float* g2      = (const float*)d_in[10];
  const float* be2     = (const float*)d_in[11];
  const float* Watt    = (const float*)d_in[12];
  const float* Wread   = (const float*)d_in[13];
  float* out = (float*)d_out;

  const int* srcIdx = ei;
  const int* dstIdx = ei + N_EDGES;

  char* p = (char*)d_ws;
  unsigned short* B0 = (unsigned short*)p; p += NS * 2;   // h (residual)
  unsigned short* B1 = (unsigned short*)p; p += NS * 2;   // Ya / T / x_bf16
  unsigned short* B2 = (unsigned short*)p; p += NS * 2;   // Yb
  unsigned short* WtE = (unsigned short*)p; p += (size_t)512 * 256 * 2;
  unsigned short* Wt1 = (unsigned short*)p; p += (size_t)3 * 512 * 1024 * 2;
  unsigned short* Wt2 = (unsigned short*)p; p += (size_t)3 * 512 * 1024 * 2;
  float* hg     = (float*)p; p += (size_t)N_GRAPH * HID * 4;
  float* sums   = (float*)p; p += 1024 * 4;
  float* invdeg = (float*)p; p += (size_t)N_NODES * 4;
  float* bcnt   = (float*)p; p += 256;
  int* deg      = (int*)p;   p += (size_t)N_NODES * 4;
  int* fillc    = (int*)p;   p += (size_t)N_NODES * 4;
  int* esrc     = (int*)p;   p += (size_t)N_EDGES * 4;
  int* rowptr   = (int*)p;   p += (size_t)(N_NODES + 1) * 4;
  int* bsum     = (int*)p;   p += (size_t)NB * 4;
  size_t need = (size_t)(p - (char*)d_ws);
  if (ws_size < need) {
    write_sentinel<<<1, 1, 0, stream>>>(out, (float)need);
    return;
  }

  // ---- weight prep (fp32 -> bf16, transposed [N][K])
  wtrans<<<dim3(8, 16), 256, 0, stream>>>(W_embed, WtE, 256, 512);
  for (int l = 0; l < 3; ++l) {
    wtrans<<<dim3(32, 16), 256, 0, stream>>>(W1 + (size_t)l * 1024 * 512,
                                             Wt1 + (size_t)l * 512 * 1024, 1024, 512);
    wtrans<<<dim3(32, 16), 256, 0, stream>>>(W2 + (size_t)l * 1024 * 512,
                                             Wt2 + (size_t)l * 512 * 1024, 1024, 512);
  }

  // ---- CSR build (parallel scan)
  hipMemsetAsync(deg, 0, N_NODES * sizeof(int), stream);
  hipMemsetAsync(fillc, 0, N_NODES * sizeof(int), stream);
  count_deg<<<(N_EDGES + 255) / 256, 256, 0, stream>>>(dstIdx, deg, N_EDGES);
  make_invdeg<<<(N_NODES + 255) / 256, 256, 0, stream>>>(deg, invdeg, N_NODES);
  scan_part<<<NB, 256, 0, stream>>>(deg, bsum, N_NODES);
  scan_bsums<<<1, 256, 0, stream>>>(bsum, NB);
  scan_final<<<NB, 256, 0, stream>>>(deg, bsum, rowptr, N_NODES);
  fill_csr<<<(N_EDGES + 255) / 256, 256, 0, stream>>>(srcIdx, dstIdx, rowptr, fillc,
                                                      esrc, N_EDGES);

  const int g1grid = 8 * 59 * 4;  // single-output GEMM grid (1888)
  const int g2grid = 8 * 59 * 8;  // dual-output GEMM grid (3776)
  const int sgrid  = (N_NODES + 63) / 64;
  const int ngrid  = (N_NODES + 3) / 4;     // aggr_norm: one wave per node
  const int bgrid  = (N_NODES + 127) / 128; // bn_stats
  const int egrid  = (int)((NS / 2 + 255) / 256);

  // ---- embed: x -> bf16 (B1), then h = x @ W_embed -> B0
  cvt_bf16<<<(int)(((size_t)N_NODES * 64 + 255) / 256), 256, 0, stream>>>(
      x, B1, (long)N_NODES * 64);
  gemm_glds<<<g1grid, 256, 0, stream>>>(B1, 256, 256, WtE, 256, nullptr, B0, N_NODES);

  for (int l = 0; l < 3; ++l) {
    const unsigned short* Wt1l = Wt1 + (size_t)l * 512 * 1024;
    const unsigned short* Wt2l = Wt2 + (size_t)l * 512 * 1024;
    // ---- SAGE 1: B1 = Ya+bias, B2 = Yb (one fused launch)
    gemm_dual<<<g2grid, 256, 0, stream>>>(B0, 512, Wt1l, b1 + l * 512, B1, B2, N_NODES);
    aggr_norm<<<ngrid, 256, 0, stream>>>(B1, B2, rowptr, esrc, invdeg, N_NODES);
    hipMemsetAsync(sums, 0, 1024 * sizeof(float), stream);
    bn_stats<<<bgrid, 256, 0, stream>>>(B1, N_NODES, sums);
    bn_apply<<<egrid, 256, 0, stream>>>(B1, B1, sums, g1 + l * 512,
                                        be1 + l * 512, N_NODES, 0);
    // ---- SAGE 2 + residual
    gemm_glds<<<g1grid, 256, 0, stream>>>(B1, 512, 512, Wt2l + 512, 1024,
                                          nullptr, B2, N_NODES);         // Yb
    gemm_strip<<<sgrid, 512, 0, stream>>>(B1, 512, Wt2l, 1024,
                                          b2 + l * 512, B1, N_NODES);    // Ya in-place
    aggr_norm<<<ngrid, 256, 0, stream>>>(B1, B2, rowptr, esrc, invdeg, N_NODES);
    hipMemsetAsync(sums, 0, 1024 * sizeof(float), stream);
    bn_stats<<<bgrid, 256, 0, stream>>>(B1, N_NODES, sums);
    bn_apply<<<egrid, 256, 0, stream>>>(B1, B0, sums, g2 + l * 512,
                                        be2 + l * 512, N_NODES, 1);
  }

  // ---- pooling + readout
  hipMemsetAsync(hg, 0, (size_t)N_GRAPH * HID * sizeof(float), stream);
  hipMemsetAsync(bcnt, 0, N_GRAPH * sizeof(float), stream);
  bcount<<<NB, 256, 0, stream>>>(batch, bcnt, N_NODES);
  att_pool2<<<(N_NODES + NPB - 1) / NPB, 256, 0, stream>>>(B0, batch, Watt, hg, N_NODES);
  readout<<<dim3(N_GRAPH, 4), 256, 0, stream>>>(hg, bcnt, Wread, out);
}

// Round 14
// 1968.314 us; speedup vs baseline: 1.2297x; 1.0586x over previous
//
#include <hip/hip_runtime.h>
#include <math.h>

#define N_NODES 60000
#define N_EDGES 360000
#define N_GRAPH 64
#define HID 512
#define NCLS 1000
#define BN_EPS 1e-5f
#define NS ((size_t)N_NODES * HID)
#define NB 235      // (N_NODES + 255) / 256
#define STRIPS 469  // ceil(60000/128)

typedef __bf16 bf16x8 __attribute__((ext_vector_type(8)));
typedef float f32x4 __attribute__((ext_vector_type(4)));

static __device__ __forceinline__ unsigned short f2bf(float f) {
  unsigned u = __float_as_uint(f);
  unsigned r = (u + 0x7fffu + ((u >> 16) & 1u)) >> 16;  // RNE
  return (unsigned short)r;
}
static __device__ __forceinline__ float bfLo(unsigned u) { return __uint_as_float(u << 16); }
static __device__ __forceinline__ float bfHi(unsigned u) { return __uint_as_float(u & 0xffff0000u); }
static __device__ __forceinline__ unsigned packbf(float a, float b) {
  return (unsigned)f2bf(a) | ((unsigned)f2bf(b) << 16);
}

__global__ void write_sentinel(float* out, float v) { out[0] = v; }

// fp32 -> bf16 elementwise convert (embed input), 4 elems/thread
__global__ __launch_bounds__(256) void cvt_bf16(const float* __restrict__ X,
                                                unsigned short* __restrict__ Y,
                                                long n4) {
  long i = (long)blockIdx.x * 256 + threadIdx.x;
  if (i >= n4) return;
  float4 f = *(const float4*)(X + i * 4);
  uint2 o;
  o.x = packbf(f.x, f.y);
  o.y = packbf(f.z, f.w);
  *(uint2*)(Y + i * 4) = o;
}

// ---------------------------------------------------------------------------
// Weight fp32 -> bf16 transpose: Wt[n][k] = bf16(W[k][n]).  32x32 tiles.
// blockIdx.z = layer (batched: strideW / strideWt elems per layer).
// ---------------------------------------------------------------------------
__global__ __launch_bounds__(256) void wtrans(const float* __restrict__ W,
                                              unsigned short* __restrict__ Wt,
                                              int K, int N,
                                              size_t strideW, size_t strideWt) {
  __shared__ float sh[32][33];
  W += (size_t)blockIdx.z * strideW;
  Wt += (size_t)blockIdx.z * strideWt;
  int kt = blockIdx.x * 32, nt = blockIdx.y * 32;
  int tx = threadIdx.x & 31, ty = threadIdx.x >> 5;  // ty 0..7
#pragma unroll
  for (int i = 0; i < 4; ++i)
    sh[ty + i * 8][tx] = W[(size_t)(kt + ty + i * 8) * N + nt + tx];
  __syncthreads();
#pragma unroll
  for (int i = 0; i < 4; ++i)
    Wt[(size_t)(nt + ty + i * 8) * K + kt + tx] = f2bf(sh[tx][ty + i * 8]);
}

// ---------------------------------------------------------------------------
// Degree / CSR build
// ---------------------------------------------------------------------------
__global__ __launch_bounds__(256) void count_deg(const int* __restrict__ dst,
                                                 int* __restrict__ deg, int E) {
  int e = blockIdx.x * 256 + threadIdx.x;
  if (e < E) atomicAdd(&deg[dst[e]], 1);
}

__global__ __launch_bounds__(256) void make_invdeg(const int* __restrict__ deg,
                                                   float* __restrict__ inv, int n) {
  int i = blockIdx.x * 256 + threadIdx.x;
  if (i < n) inv[i] = 1.0f / fmaxf((float)deg[i], 1.0f);
}

__global__ __launch_bounds__(256) void scan_part(const int* __restrict__ deg,
                                                 int* __restrict__ bsum, int n) {
  __shared__ int sh[256];
  int i = blockIdx.x * 256 + threadIdx.x;
  sh[threadIdx.x] = (i < n) ? deg[i] : 0;
  __syncthreads();
  for (int off = 128; off; off >>= 1) {
    if (threadIdx.x < off) sh[threadIdx.x] += sh[threadIdx.x + off];
    __syncthreads();
  }
  if (threadIdx.x == 0) bsum[blockIdx.x] = sh[0];
}

__global__ __launch_bounds__(256) void scan_bsums(int* __restrict__ bsum, int nb) {
  __shared__ int sh[256];
  int t = threadIdx.x;
  int v = (t < nb) ? bsum[t] : 0;
  sh[t] = v;
  __syncthreads();
  for (int off = 1; off < 256; off <<= 1) {
    int u = (t >= off) ? sh[t - off] : 0;
    __syncthreads();
    sh[t] += u;
    __syncthreads();
  }
  if (t < nb) bsum[t] = sh[t] - v;  // exclusive
}

__global__ __launch_bounds__(256) void scan_final(const int* __restrict__ deg,
                                                  const int* __restrict__ bsum,
                                                  int* __restrict__ rowptr, int n) {
  __shared__ int sh[256];
  int t = threadIdx.x;
  int i = blockIdx.x * 256 + t;
  int v = (i < n) ? deg[i] : 0;
  sh[t] = v;
  __syncthreads();
  for (int off = 1; off < 256; off <<= 1) {
    int u = (t >= off) ? sh[t - off] : 0;
    __syncthreads();
    sh[t] += u;
    __syncthreads();
  }
  if (i < n) rowptr[i + 1] = bsum[blockIdx.x] + sh[t];
  if (i == 0) rowptr[0] = 0;
}

__global__ __launch_bounds__(256) void fill_csr(const int* __restrict__ src,
                                                const int* __restrict__ dst,
                                                const int* __restrict__ rowptr,
                                                int* __restrict__ fillc,
                                                int* __restrict__ esrc, int E) {
  int e = blockIdx.x * 256 + threadIdx.x;
  if (e < E) {
    int d = dst[e];
    int pos = rowptr[d] + atomicAdd(&fillc[d], 1);
    esrc[pos] = src[e];
  }
}

// LDS-histogram batch count
__global__ __launch_bounds__(256) void bcount(const int* __restrict__ batch,
                                              float* __restrict__ bcnt, int n) {
  __shared__ int h[N_GRAPH];
  if (threadIdx.x < N_GRAPH) h[threadIdx.x] = 0;
  __syncthreads();
  int i = blockIdx.x * 256 + threadIdx.x;
  if (i < n) atomicAdd(&h[batch[i]], 1);
  __syncthreads();
  if (threadIdx.x < N_GRAPH && h[threadIdx.x])
    atomicAdd(&bcnt[threadIdx.x], (float)h[threadIdx.x]);
}

// ---------------------------------------------------------------------------
// Shared GEMM block body (m97 structure, R11-verified):
// 128x128 tile, BK=32, 4 waves; glds lane-remap staging (0 conflicts),
// LDS-bounce epilogue (coalesced uint4 stores).
// ---------------------------------------------------------------------------
#define GEMM_BODY(Xb, ldx, Wtb, ldw, bias_p, outp, KDIM)                        \
  const int wv = tid >> 6, lane = tid & 63;                                     \
  const int wm = (wv >> 1) * 64, wn = (wv & 1) * 64;                            \
  const int lm = lane & 15, quad = lane >> 4;                                   \
  const int grow = lane & 15, gseg = (lane >> 4) * 8;                           \
  f32x4 zero; zero[0] = 0.f; zero[1] = 0.f; zero[2] = 0.f; zero[3] = 0.f;       \
  f32x4 acc[4][4];                                                              \
  _Pragma("unroll") for (int i = 0; i < 4; ++i)                                 \
    _Pragma("unroll") for (int j = 0; j < 4; ++j) acc[i][j] = zero;             \
  for (int kt = 0; kt < (KDIM); kt += 32) {                                     \
    __syncthreads();                                                            \
    _Pragma("unroll") for (int r = 0; r < 2; ++r) {                             \
      int chunk = wv + r * 4;                                                   \
      int row = chunk * 16 + grow;                                              \
      const unsigned short* ga = (Xb) + (size_t)(bm + row) * (ldx) + kt + gseg; \
      const unsigned short* gb = (Wtb) + (size_t)(bn + row) * (ldw) + kt + gseg;\
      __builtin_amdgcn_global_load_lds(                                         \
          (const __attribute__((address_space(1))) unsigned int*)ga,            \
          (__attribute__((address_space(3))) unsigned int*)(As + chunk * 512),  \
          16, 0, 0);                                                            \
      __builtin_amdgcn_global_load_lds(                                         \
          (const __attribute__((address_space(1))) unsigned int*)gb,            \
          (__attribute__((address_space(3))) unsigned int*)(Bs + chunk * 512),  \
          16, 0, 0);                                                            \
    }                                                                           \
    __syncthreads();                                                            \
    bf16x8 af[4], bfr[4];                                                       \
    _Pragma("unroll") for (int i = 0; i < 4; ++i)                               \
      af[i] = *(const bf16x8*)(As + (wm / 16 + i) * 512 + lane * 8);            \
    _Pragma("unroll") for (int j = 0; j < 4; ++j)                               \
      bfr[j] = *(const bf16x8*)(Bs + (wn / 16 + j) * 512 + lane * 8);           \
    _Pragma("unroll") for (int i = 0; i < 4; ++i)                               \
      _Pragma("unroll") for (int j = 0; j < 4; ++j)                             \
        acc[i][j] = __builtin_amdgcn_mfma_f32_16x16x32_bf16(af[i], bfr[j],      \
                                                            acc[i][j], 0, 0, 0);\
  }                                                                             \
  const int qr = quad * 4;                                                      \
  const int rl = tid >> 4, seg = (tid & 15) * 8;                                \
  _Pragma("unroll") for (int p = 0; p < 2; ++p) {                               \
    __syncthreads();                                                            \
    if ((wv >> 1) == p) {                                                       \
      _Pragma("unroll") for (int j = 0; j < 4; ++j) {                           \
        int col = wn + j * 16 + lm;                                             \
        float bvv = (bias_p) ? (bias_p)[bn + col] : 0.f;                        \
        _Pragma("unroll") for (int i = 0; i < 4; ++i)                           \
          _Pragma("unroll") for (int r = 0; r < 4; ++r)                         \
            Cs[i * 16 + qr + r][col] = f2bf(acc[i][j][r] + bvv);                \
      }                                                                         \
    }                                                                           \
    __syncthreads();                                                            \
    _Pragma("unroll") for (int pass = 0; pass < 4; ++pass) {                    \
      int row = bm + p * 64 + pass * 16 + rl;                                   \
      if (row < M)                                                              \
        *(uint4*)((outp) + (size_t)row * 512 + bn + seg) =                      \
            *(const uint4*)(&Cs[pass * 16 + rl][seg]);                          \
    }                                                                           \
  }

// single-output GEMM (embed K=256, SAGE2-Yb K=512); XCD-swizzled 1-D grid
__global__ __launch_bounds__(256) void gemm_glds(
    const unsigned short* __restrict__ Xb, int ldx, int K,
    const unsigned short* __restrict__ Wt, int ldw,
    const float* __restrict__ bias,
    unsigned short* __restrict__ outB, int M) {
  __shared__ __align__(16) unsigned short As[128 * 32];
  __shared__ __align__(16) unsigned short Bs[128 * 32];
  __shared__ __align__(16) unsigned short Cs[64][136];
  const int tid = threadIdx.x;
  const int L = blockIdx.x;
  const int xcd = L & 7, li = L >> 3;
  const int strip = xcd * 59 + (li >> 2);
  if (strip >= STRIPS) return;
  const int bm = strip * 128;
  const int bn = (li & 3) * 128;
  GEMM_BODY(Xb, ldx, Wt, ldw, bias, outB, K)
}

// dual-output GEMM: k 0..511 of Wt -> outA(+bias), k 512..1023 -> outB.
__global__ __launch_bounds__(256) void gemm_dual(
    const unsigned short* __restrict__ Xb, int ldx,
    const unsigned short* __restrict__ Wt,  // [512][1024]
    const float* __restrict__ biasA,
    unsigned short* __restrict__ outA, unsigned short* __restrict__ outBf,
    int M) {
  __shared__ __align__(16) unsigned short As[128 * 32];
  __shared__ __align__(16) unsigned short Bs[128 * 32];
  __shared__ __align__(16) unsigned short Cs[64][136];
  const int tid = threadIdx.x;
  const int L = blockIdx.x;
  const int xcd = L & 7, li = L >> 3;
  const int strip = xcd * 59 + (li >> 3);
  if (strip >= STRIPS) return;
  const int cb = li & 7;
  const int bm = strip * 128;
  const int bn = (cb & 3) * 128;
  const unsigned short* Wtb = Wt + (cb < 4 ? 0 : 512);
  const float* bias = (cb < 4) ? biasA : nullptr;
  unsigned short* outp = (cb < 4) ? outA : outBf;
  GEMM_BODY(Xb, ldx, Wtb, 1024, bias, outp, 512)
}

// ---------------------------------------------------------------------------
// Row-strip MFMA GEMM — IN-PLACE SAFE fallback (SAGE2 Ya when B3 absent).
// ---------------------------------------------------------------------------
__global__ __launch_bounds__(512) void gemm_strip(
    const unsigned short* __restrict__ Xb, int ldx,
    const unsigned short* __restrict__ Wt, int ldw,
    const float* __restrict__ bias,
    unsigned short* __restrict__ outB, int M) {
  __shared__ __align__(16) unsigned short As[64][40];
  const int tid = threadIdx.x;
  const int bm = blockIdx.x * 64;
  const int wv = tid >> 6, lane = tid & 63;
  const int lm = lane & 15, quad = lane >> 4, lk = quad * 8;
  const int cb = wv * 64;
  const int arow = tid >> 3, aseg = (tid & 7) * 4;

  f32x4 zero;
  zero[0] = 0.f; zero[1] = 0.f; zero[2] = 0.f; zero[3] = 0.f;
  f32x4 acc[4][4];
#pragma unroll
  for (int i = 0; i < 4; ++i)
#pragma unroll
    for (int j = 0; j < 4; ++j) acc[i][j] = zero;

  for (int kt = 0; kt < 512; kt += 32) {
    uint2 av = make_uint2(0, 0);
    int gr = bm + arow;
    if (gr < M) av = *(const uint2*)(Xb + (size_t)gr * ldx + kt + aseg);
    bf16x8 bfr[4];
#pragma unroll
    for (int j = 0; j < 4; ++j)
      bfr[j] = *(const bf16x8*)(Wt + (size_t)(cb + j * 16 + lm) * ldw + kt + lk);
    __syncthreads();
    *(uint2*)(&As[arow][aseg]) = av;
    __syncthreads();
    bf16x8 af[4];
#pragma unroll
    for (int i = 0; i < 4; ++i) af[i] = *(const bf16x8*)(&As[i * 16 + lm][lk]);
#pragma unroll
    for (int i = 0; i < 4; ++i)
#pragma unroll
      for (int j = 0; j < 4; ++j)
        acc[i][j] = __builtin_amdgcn_mfma_f32_16x16x32_bf16(af[i], bfr[j], acc[i][j], 0, 0, 0);
  }

  const int qr = quad * 4;
#pragma unroll
  for (int j = 0; j < 4; ++j) {
    int col = cb + j * 16 + lm;
    float bvv = bias ? bias[col] : 0.f;
#pragma unroll
    for (int i = 0; i < 4; ++i) {
      int rbase = bm + i * 16 + qr;
#pragma unroll
      for (int r = 0; r < 4; ++r) {
        int row = rbase + r;
        if (row < M) outB[(size_t)row * 512 + col] = f2bf(acc[i][j][r] + bvv);
      }
    }
  }
}

// ---------------------------------------------------------------------------
// Fused aggregation + L2 row-norm (one wave per node — R11/R13-proven).
// ---------------------------------------------------------------------------
__global__ __launch_bounds__(256) void aggr_norm(
    unsigned short* __restrict__ Ya, const unsigned short* __restrict__ Yb,
    const int* __restrict__ rowptr, const int* __restrict__ esrc,
    const float* __restrict__ invdeg, int M) {
  int d = blockIdx.x * 4 + (threadIdx.x >> 6);
  int lane = threadIdx.x & 63;
  if (d >= M) return;
  float acc[8] = {0.f, 0.f, 0.f, 0.f, 0.f, 0.f, 0.f, 0.f};
  int beg = rowptr[d], end = rowptr[d + 1];
  for (int e = beg; e < end; ++e) {
    int s = esrc[e];
    uint4 u = *(const uint4*)(Yb + (size_t)s * 512 + lane * 8);
    acc[0] += bfLo(u.x); acc[1] += bfHi(u.x);
    acc[2] += bfLo(u.y); acc[3] += bfHi(u.y);
    acc[4] += bfLo(u.z); acc[5] += bfHi(u.z);
    acc[6] += bfLo(u.w); acc[7] += bfHi(u.w);
  }
  float iv = invdeg[d];
  uint4 a = *(const uint4*)(Ya + (size_t)d * 512 + lane * 8);
  float r0 = bfLo(a.x) + iv * acc[0], r1 = bfHi(a.x) + iv * acc[1];
  float r2 = bfLo(a.y) + iv * acc[2], r3 = bfHi(a.y) + iv * acc[3];
  float r4 = bfLo(a.z) + iv * acc[4], r5 = bfHi(a.z) + iv * acc[5];
  float r6 = bfLo(a.w) + iv * acc[6], r7 = bfHi(a.w) + iv * acc[7];
  float ss = r0 * r0 + r1 * r1 + r2 * r2 + r3 * r3
           + r4 * r4 + r5 * r5 + r6 * r6 + r7 * r7;
#pragma unroll
  for (int o = 32; o; o >>= 1) ss += __shfl_xor(ss, o, 64);
  float inv = 1.0f / fmaxf(sqrtf(ss), 1e-12f);
  uint4 o4;
  o4.x = packbf(r0 * inv, r1 * inv);
  o4.y = packbf(r2 * inv, r3 * inv);
  o4.z = packbf(r4 * inv, r5 * inv);
  o4.w = packbf(r6 * inv, r7 * inv);
  *(uint4*)(Ya + (size_t)d * 512 + lane * 8) = o4;
}

// ---------------------------------------------------------------------------
// BN stats over bf16: 32 rows/block (4x the R13 parallelism: 1875 blocks;
// atomics 1.9M over 1024 addrs -- ~us-scale; read path was the bottleneck).
// ---------------------------------------------------------------------------
__global__ __launch_bounds__(256) void bn_stats(const unsigned short* __restrict__ T,
                                                int M, float* __restrict__ sums) {
  const int t = threadIdx.x;
  int r0 = blockIdx.x * 32;
  int rend = min(r0 + 32, M);
  float s0 = 0.f, q0 = 0.f, s1 = 0.f, q1 = 0.f;
  for (int r = r0; r < rend; ++r) {
    float a = __uint_as_float((unsigned)T[(size_t)r * 512 + t] << 16);
    float b = __uint_as_float((unsigned)T[(size_t)r * 512 + t + 256] << 16);
    s0 += a; q0 += a * a; s1 += b; q1 += b * b;
  }
  atomicAdd(&sums[t], s0);
  atomicAdd(&sums[t + 256], s1);
  atomicAdd(&sums[512 + t], q0);
  atomicAdd(&sums[512 + t + 256], q1);
}

// BN apply + ReLU (+ optional residual); uint4-vectorized (8 bf16/thread).
__global__ __launch_bounds__(256) void bn_apply(const unsigned short* __restrict__ U,
                                                unsigned short* __restrict__ H,
                                                const float* __restrict__ sums,
                                                const float* __restrict__ g,
                                                const float* __restrict__ be,
                                                int M, int residual) {
  size_t i4 = (size_t)blockIdx.x * 256 + threadIdx.x;
  if (i4 >= NS / 8) return;
  int c = (int)((i4 * 8) & 511);
  float invM = 1.0f / (float)M;
  uint4 u4 = ((const uint4*)U)[i4];
  uint4 h4;
  if (residual) h4 = ((const uint4*)H)[i4];
  unsigned uin[4] = {u4.x, u4.y, u4.z, u4.w};
  unsigned hin[4] = {h4.x, h4.y, h4.z, h4.w};
  unsigned outv[4];
#pragma unroll
  for (int k = 0; k < 4; ++k) {
    int c0 = c + k * 2;
    float m0 = sums[c0] * invM, m1 = sums[c0 + 1] * invM;
    float v0 = sums[512 + c0] * invM - m0 * m0;
    float v1 = sums[512 + c0 + 1] * invM - m1 * m1;
    float k0 = rsqrtf(v0 + BN_EPS) * g[c0], k1 = rsqrtf(v1 + BN_EPS) * g[c0 + 1];
    float x0 = fmaxf((bfLo(uin[k]) - m0) * k0 + be[c0], 0.f);
    float x1 = fmaxf((bfHi(uin[k]) - m1) * k1 + be[c0 + 1], 0.f);
    if (residual) { x0 += bfLo(hin[k]); x1 += bfHi(hin[k]); }
    outv[k] = packbf(x0, x1);
  }
  uint4 o4 = make_uint4(outv[0], outv[1], outv[2], outv[3]);
  ((uint4*)H)[i4] = o4;
}

// ---------------------------------------------------------------------------
// Attention pool, sorted-batch segmented, 64 nodes/block (938 blocks).
// ---------------------------------------------------------------------------
#define NPB 64
__global__ __launch_bounds__(256) void att_pool2(const unsigned short* __restrict__ H,
                                                 const int* __restrict__ batch,
                                                 const float* __restrict__ Watt,
                                                 float* __restrict__ hg, int M) {
  __shared__ float fsh[NPB];
  __shared__ int bsh[NPB];
  const int tid = threadIdx.x;
  const int base = blockIdx.x * NPB;
  if (tid < NPB) bsh[tid] = (base + tid < M) ? batch[base + tid] : -1;
  const int wv = tid >> 6, lane = tid & 63;
  float4 wa0 = *(const float4*)(Watt + lane * 8);
  float4 wa1 = *(const float4*)(Watt + lane * 8 + 4);
  __syncthreads();
  for (int i = wv; i < NPB; i += 4) {
    int node = base + i;
    float dot = 0.f;
    if (node < M) {
      uint4 u = *(const uint4*)(H + (size_t)node * 512 + lane * 8);
      dot = bfLo(u.x) * wa0.x + bfHi(u.x) * wa0.y
          + bfLo(u.y) * wa0.z + bfHi(u.y) * wa0.w
          + bfLo(u.z) * wa1.x + bfHi(u.z) * wa1.y
          + bfLo(u.w) * wa1.z + bfHi(u.w) * wa1.w;
    }
#pragma unroll
    for (int o = 32; o; o >>= 1) dot += __shfl_xor(dot, o, 64);
    if (lane == 0) fsh[i] = 0.5f * (1.0f + 1.0f / (1.0f + expf(-dot)));
  }
  __syncthreads();
  float a0 = 0.f, a1 = 0.f;
  int cur = bsh[0];
  for (int i = 0; i < NPB; ++i) {
    int node = base + i;
    if (node >= M) break;
    int b = bsh[i];
    if (b != cur) {
      atomicAdd(&hg[(size_t)cur * 512 + tid * 2], a0);
      atomicAdd(&hg[(size_t)cur * 512 + tid * 2 + 1], a1);
      a0 = a1 = 0.f;
      cur = b;
    }
    unsigned u = *(const unsigned*)(H + (size_t)node * 512 + tid * 2);
    float f = fsh[i];
    a0 += bfLo(u) * f;
    a1 += bfHi(u) * f;
  }
  if (cur >= 0) {
    atomicAdd(&hg[(size_t)cur * 512 + tid * 2], a0);
    atomicAdd(&hg[(size_t)cur * 512 + tid * 2 + 1], a1);
  }
}

// ---------------------------------------------------------------------------
// Readout: out[g, n] = (hg[g]/bcnt[g]) . Wread[:, n]
// ---------------------------------------------------------------------------
__global__ __launch_bounds__(256) void readout(const float* __restrict__ hg,
                                               const float* __restrict__ bcnt,
                                               const float* __restrict__ Wr,
                                               float* __restrict__ out) {
  __shared__ float sh[HID];
  int g = blockIdx.x;
  int n = blockIdx.y * 256 + threadIdx.x;
  float inv = 1.0f / fmaxf(bcnt[g], 1.0f);
  for (int k = threadIdx.x; k < HID; k += 256) sh[k] = hg[(size_t)g * HID + k] * inv;
  __syncthreads();
  if (n < NCLS) {
    float acc = 0.f;
    for (int k = 0; k < HID; ++k) acc += sh[k] * Wr[(size_t)k * NCLS + n];
    out[(size_t)g * NCLS + n] = acc;
  }
}

// ---------------------------------------------------------------------------
extern "C" void kernel_launch(void* const* d_in, const int* in_sizes, int n_in,
                              void* d_out, int out_size, void* d_ws, size_t ws_size,
                              hipStream_t stream) {
  const float* x       = (const float*)d_in[0];
  const int*   ei      = (const int*)d_in[1];
  const int*   batch   = (const int*)d_in[2];
  const float* W_embed = (const float*)d_in[3];
  const float* W1      = (const float*)d_in[4];
  const float* b1      = (const float*)d_in[5];
  const float* g1      = (const float*)d_in[6];
  const float* be1     = (const float*)d_in[7];
  const float* W2      = (const float*)d_in[8];
  const float* b2      = (const float*)d_in[9];
  const float* g2      = (const float*)d_in[10];
  const float* be2     = (const float*)d_in[11];
  const float* Watt    = (const float*)d_in[12];
  const float* Wread   = (const float*)d_in[13];
  float* out = (float*)d_out;

  const int* srcIdx = ei;
  const int* dstIdx = ei + N_EDGES;

  char* p = (char*)d_ws;
  unsigned short* B0 = (unsigned short*)p; p += NS * 2;   // h (residual)
  unsigned short* B1 = (unsigned short*)p; p += NS * 2;   // Ya / T / x_bf16
  unsigned short* B2 = (unsigned short*)p; p += NS * 2;   // Yb
  unsigned short* WtE = (unsigned short*)p; p += (size_t)512 * 256 * 2;
  unsigned short* Wt1 = (unsigned short*)p; p += (size_t)3 * 512 * 1024 * 2;
  unsigned short* Wt2 = (unsigned short*)p; p += (size_t)3 * 512 * 1024 * 2;
  float* hg     = (float*)p; p += (size_t)N_GRAPH * HID * 4;
  float* sums   = (float*)p; p += 1024 * 4;
  float* invdeg = (float*)p; p += (size_t)N_NODES * 4;
  float* bcnt   = (float*)p; p += 256;
  int* deg      = (int*)p;   p += (size_t)N_NODES * 4;
  int* fillc    = (int*)p;   p += (size_t)N_NODES * 4;
  int* esrc     = (int*)p;   p += (size_t)N_EDGES * 4;
  int* rowptr   = (int*)p;   p += (size_t)(N_NODES + 1) * 4;
  int* bsum     = (int*)p;   p += (size_t)NB * 4;
  size_t need = (size_t)(p - (char*)d_ws);
  if (ws_size < need) {
    write_sentinel<<<1, 1, 0, stream>>>(out, (float)need);
    return;
  }
  // optional 4th activation buffer -> SAGE2 also runs as a single gemm_dual
  unsigned short* B3 = nullptr;
  if (ws_size >= need + NS * 2) B3 = (unsigned short*)((char*)d_ws + need);

  // ---- weight prep (fp32 -> bf16, transposed [N][K]); layer-batched
  wtrans<<<dim3(8, 16, 1), 256, 0, stream>>>(W_embed, WtE, 256, 512, 0, 0);
  wtrans<<<dim3(32, 16, 3), 256, 0, stream>>>(W1, Wt1, 1024, 512,
                                              (size_t)1024 * 512, (size_t)512 * 1024);
  wtrans<<<dim3(32, 16, 3), 256, 0, stream>>>(W2, Wt2, 1024, 512,
                                              (size_t)1024 * 512, (size_t)512 * 1024);

  // ---- CSR build (parallel scan)
  hipMemsetAsync(deg, 0, N_NODES * sizeof(int), stream);
  hipMemsetAsync(fillc, 0, N_NODES * sizeof(int), stream);
  count_deg<<<(N_EDGES + 255) / 256, 256, 0, stream>>>(dstIdx, deg, N_EDGES);
  make_invdeg<<<(N_NODES + 255) / 256, 256, 0, stream>>>(deg, invdeg, N_NODES);
  scan_part<<<NB, 256, 0, stream>>>(deg, bsum, N_NODES);
  scan_bsums<<<1, 256, 0, stream>>>(bsum, NB);
  scan_final<<<NB, 256, 0, stream>>>(deg, bsum, rowptr, N_NODES);
  fill_csr<<<(N_EDGES + 255) / 256, 256, 0, stream>>>(srcIdx, dstIdx, rowptr, fillc,
                                                      esrc, N_EDGES);

  const int g1grid = 8 * 59 * 4;  // single-output GEMM grid (1888)
  const int g2grid = 8 * 59 * 8;  // dual-output GEMM grid (3776)
  const int sgrid  = (N_NODES + 63) / 64;
  const int ngrid  = (N_NODES + 3) / 4;     // aggr_norm: one wave per node
  const int bgrid  = (N_NODES + 31) / 32;   // bn_stats: 32 rows/block
  const int egrid  = (int)((NS / 8 + 255) / 256);

  // ---- embed: x -> bf16 (B1), then h = x @ W_embed -> B0
  cvt_bf16<<<(int)(((size_t)N_NODES * 64 + 255) / 256), 256, 0, stream>>>(
      x, B1, (long)N_NODES * 64);
  gemm_glds<<<g1grid, 256, 0, stream>>>(B1, 256, 256, WtE, 256, nullptr, B0, N_NODES);

  for (int l = 0; l < 3; ++l) {
    const unsigned short* Wt1l = Wt1 + (size_t)l * 512 * 1024;
    const unsigned short* Wt2l = Wt2 + (size_t)l * 512 * 1024;
    // ---- SAGE 1: B1 = Ya+bias, B2 = Yb (one fused launch)
    gemm_dual<<<g2grid, 256, 0, stream>>>(B0, 512, Wt1l, b1 + l * 512, B1, B2, N_NODES);
    aggr_norm<<<ngrid, 256, 0, stream>>>(B1, B2, rowptr, esrc, invdeg, N_NODES);
    hipMemsetAsync(sums, 0, 1024 * sizeof(float), stream);
    bn_stats<<<bgrid, 256, 0, stream>>>(B1, N_NODES, sums);
    bn_apply<<<egrid, 256, 0, stream>>>(B1, B1, sums, g1 + l * 512,
                                        be1 + l * 512, N_NODES, 0);
    // ---- SAGE 2 + residual
    unsigned short* Ya2 = B3 ? B3 : B1;
    if (B3) {
      gemm_dual<<<g2grid, 256, 0, stream>>>(B1, 512, Wt2l, b2 + l * 512, B3, B2,
                                            N_NODES);
    } else {
      gemm_glds<<<g1grid, 256, 0, stream>>>(B1, 512, 512, Wt2l + 512, 1024,
                                            nullptr, B2, N_NODES);       // Yb
      gemm_strip<<<sgrid, 512, 0, stream>>>(B1, 512, Wt2l, 1024,
                                            b2 + l * 512, B1, N_NODES);  // Ya in-place
    }
    aggr_norm<<<ngrid, 256, 0, stream>>>(Ya2, B2, rowptr, esrc, invdeg, N_NODES);
    hipMemsetAsync(sums, 0, 1024 * sizeof(float), stream);
    bn_stats<<<bgrid, 256, 0, stream>>>(Ya2, N_NODES, sums);
    bn_apply<<<egrid, 256, 0, stream>>>(Ya2, B0, sums, g2 + l * 512,
                                        be2 + l * 512, N_NODES, 1);
  }

  // ---- pooling + readout
  hipMemsetAsync(hg, 0, (size_t)N_GRAPH * HID * sizeof(float), stream);
  hipMemsetAsync(bcnt, 0, N_GRAPH * sizeof(float), stream);
  bcount<<<NB, 256, 0, stream>>>(batch, bcnt, N_NODES);
  att_pool2<<<(N_NODES + NPB - 1) / NPB, 256, 0, stream>>>(B0, batch, Watt, hg, N_NODES);
  readout<<<dim3(N_GRAPH, 4), 256, 0, stream>>>(hg, bcnt, Wread, out);
}

// Round 15
// 1963.384 us; speedup vs baseline: 1.2328x; 1.0025x over previous
//
#include <hip/hip_runtime.h>
#include <math.h>

#define N_NODES 60000
#define N_EDGES 360000
#define N_GRAPH 64
#define HID 512
#define NCLS 1000
#define BN_EPS 1e-5f
#define NS ((size_t)N_NODES * HID)
#define NB 235      // (N_NODES + 255) / 256
#define STRIPS 469  // ceil(60000/128)

typedef __bf16 bf16x8 __attribute__((ext_vector_type(8)));
typedef float f32x4 __attribute__((ext_vector_type(4)));

static __device__ __forceinline__ unsigned short f2bf(float f) {
  unsigned u = __float_as_uint(f);
  unsigned r = (u + 0x7fffu + ((u >> 16) & 1u)) >> 16;  // RNE
  return (unsigned short)r;
}
static __device__ __forceinline__ float bfLo(unsigned u) { return __uint_as_float(u << 16); }
static __device__ __forceinline__ float bfHi(unsigned u) { return __uint_as_float(u & 0xffff0000u); }
static __device__ __forceinline__ unsigned packbf(float a, float b) {
  return (unsigned)f2bf(a) | ((unsigned)f2bf(b) << 16);
}

__global__ void write_sentinel(float* out, float v) { out[0] = v; }

// fp32 -> bf16 elementwise convert (embed input), 4 elems/thread
__global__ __launch_bounds__(256) void cvt_bf16(const float* __restrict__ X,
                                                unsigned short* __restrict__ Y,
                                                long n4) {
  long i = (long)blockIdx.x * 256 + threadIdx.x;
  if (i >= n4) return;
  float4 f = *(const float4*)(X + i * 4);
  uint2 o;
  o.x = packbf(f.x, f.y);
  o.y = packbf(f.z, f.w);
  *(uint2*)(Y + i * 4) = o;
}

// ---------------------------------------------------------------------------
// Weight fp32 -> bf16 transpose: Wt[n][k] = bf16(W[k][n]).  32x32 tiles.
// blockIdx.z = layer (batched).
// ---------------------------------------------------------------------------
__global__ __launch_bounds__(256) void wtrans(const float* __restrict__ W,
                                              unsigned short* __restrict__ Wt,
                                              int K, int N,
                                              size_t strideW, size_t strideWt) {
  __shared__ float sh[32][33];
  W += (size_t)blockIdx.z * strideW;
  Wt += (size_t)blockIdx.z * strideWt;
  int kt = blockIdx.x * 32, nt = blockIdx.y * 32;
  int tx = threadIdx.x & 31, ty = threadIdx.x >> 5;  // ty 0..7
#pragma unroll
  for (int i = 0; i < 4; ++i)
    sh[ty + i * 8][tx] = W[(size_t)(kt + ty + i * 8) * N + nt + tx];
  __syncthreads();
#pragma unroll
  for (int i = 0; i < 4; ++i)
    Wt[(size_t)(nt + ty + i * 8) * K + kt + tx] = f2bf(sh[tx][ty + i * 8]);
}

// ---------------------------------------------------------------------------
// Degree / CSR build
// ---------------------------------------------------------------------------
__global__ __launch_bounds__(256) void count_deg(const int* __restrict__ dst,
                                                 int* __restrict__ deg, int E) {
  int e = blockIdx.x * 256 + threadIdx.x;
  if (e < E) atomicAdd(&deg[dst[e]], 1);
}

__global__ __launch_bounds__(256) void make_invdeg(const int* __restrict__ deg,
                                                   float* __restrict__ inv, int n) {
  int i = blockIdx.x * 256 + threadIdx.x;
  if (i < n) inv[i] = 1.0f / fmaxf((float)deg[i], 1.0f);
}

__global__ __launch_bounds__(256) void scan_part(const int* __restrict__ deg,
                                                 int* __restrict__ bsum, int n) {
  __shared__ int sh[256];
  int i = blockIdx.x * 256 + threadIdx.x;
  sh[threadIdx.x] = (i < n) ? deg[i] : 0;
  __syncthreads();
  for (int off = 128; off; off >>= 1) {
    if (threadIdx.x < off) sh[threadIdx.x] += sh[threadIdx.x + off];
    __syncthreads();
  }
  if (threadIdx.x == 0) bsum[blockIdx.x] = sh[0];
}

__global__ __launch_bounds__(256) void scan_bsums(int* __restrict__ bsum, int nb) {
  __shared__ int sh[256];
  int t = threadIdx.x;
  int v = (t < nb) ? bsum[t] : 0;
  sh[t] = v;
  __syncthreads();
  for (int off = 1; off < 256; off <<= 1) {
    int u = (t >= off) ? sh[t - off] : 0;
    __syncthreads();
    sh[t] += u;
    __syncthreads();
  }
  if (t < nb) bsum[t] = sh[t] - v;  // exclusive
}

__global__ __launch_bounds__(256) void scan_final(const int* __restrict__ deg,
                                                  const int* __restrict__ bsum,
                                                  int* __restrict__ rowptr, int n) {
  __shared__ int sh[256];
  int t = threadIdx.x;
  int i = blockIdx.x * 256 + t;
  int v = (i < n) ? deg[i] : 0;
  sh[t] = v;
  __syncthreads();
  for (int off = 1; off < 256; off <<= 1) {
    int u = (t >= off) ? sh[t - off] : 0;
    __syncthreads();
    sh[t] += u;
    __syncthreads();
  }
  if (i < n) rowptr[i + 1] = bsum[blockIdx.x] + sh[t];
  if (i == 0) rowptr[0] = 0;
}

__global__ __launch_bounds__(256) void fill_csr(const int* __restrict__ src,
                                                const int* __restrict__ dst,
                                                const int* __restrict__ rowptr,
                                                int* __restrict__ fillc,
                                                int* __restrict__ esrc, int E) {
  int e = blockIdx.x * 256 + threadIdx.x;
  if (e < E) {
    int d = dst[e];
    int pos = rowptr[d] + atomicAdd(&fillc[d], 1);
    esrc[pos] = src[e];
  }
}

// LDS-histogram batch count
__global__ __launch_bounds__(256) void bcount(const int* __restrict__ batch,
                                              float* __restrict__ bcnt, int n) {
  __shared__ int h[N_GRAPH];
  if (threadIdx.x < N_GRAPH) h[threadIdx.x] = 0;
  __syncthreads();
  int i = blockIdx.x * 256 + threadIdx.x;
  if (i < n) atomicAdd(&h[batch[i]], 1);
  __syncthreads();
  if (threadIdx.x < N_GRAPH && h[threadIdx.x])
    atomicAdd(&bcnt[threadIdx.x], (float)h[threadIdx.x]);
}

// ---------------------------------------------------------------------------
// Shared GEMM block body (m97 structure). LDS layout: single 17408B block;
// As @0 (8192B), Bs @8192 (8192B); Cs (64x136 halfs, 17408B) ALIASES As/Bs —
// legal because the epilogue's first __syncthreads separates all k-loop LDS
// reads from Cs writes. Halves LDS/block (33.8->17.4KB) -> 6 blocks/CU
// (VGPR-capped) vs 4, for latency hiding of the vmcnt(0) barrier drains.
// ---------------------------------------------------------------------------
#define GEMM_BODY(Xb, ldx, Wtb, ldw, bias_p, outp, KDIM)                        \
  unsigned short* As = (unsigned short*)smem;                                   \
  unsigned short* Bs = (unsigned short*)(smem + 8192);                          \
  typedef unsigned short CsRow[136];                                            \
  CsRow* Cs = (CsRow*)smem;                                                     \
  const int wv = tid >> 6, lane = tid & 63;                                     \
  const int wm = (wv >> 1) * 64, wn = (wv & 1) * 64;                            \
  const int lm = lane & 15, quad = lane >> 4;                                   \
  const int grow = lane & 15, gseg = (lane >> 4) * 8;                           \
  f32x4 zero; zero[0] = 0.f; zero[1] = 0.f; zero[2] = 0.f; zero[3] = 0.f;       \
  f32x4 acc[4][4];                                                              \
  _Pragma("unroll") for (int i = 0; i < 4; ++i)                                 \
    _Pragma("unroll") for (int j = 0; j < 4; ++j) acc[i][j] = zero;             \
  for (int kt = 0; kt < (KDIM); kt += 32) {                                     \
    __syncthreads();                                                            \
    _Pragma("unroll") for (int r = 0; r < 2; ++r) {                             \
      int chunk = wv + r * 4;                                                   \
      int row = chunk * 16 + grow;                                              \
      const unsigned short* ga = (Xb) + (size_t)(bm + row) * (ldx) + kt + gseg; \
      const unsigned short* gb = (Wtb) + (size_t)(bn + row) * (ldw) + kt + gseg;\
      __builtin_amdgcn_global_load_lds(                                         \
          (const __attribute__((address_space(1))) unsigned int*)ga,            \
          (__attribute__((address_space(3))) unsigned int*)(As + chunk * 512),  \
          16, 0, 0);                                                            \
      __builtin_amdgcn_global_load_lds(                                         \
          (const __attribute__((address_space(1))) unsigned int*)gb,            \
          (__attribute__((address_space(3))) unsigned int*)(Bs + chunk * 512),  \
          16, 0, 0);                                                            \
    }                                                                           \
    __syncthreads();                                                            \
    bf16x8 af[4], bfr[4];                                                       \
    _Pragma("unroll") for (int i = 0; i < 4; ++i)                               \
      af[i] = *(const bf16x8*)(As + (wm / 16 + i) * 512 + lane * 8);            \
    _Pragma("unroll") for (int j = 0; j < 4; ++j)                               \
      bfr[j] = *(const bf16x8*)(Bs + (wn / 16 + j) * 512 + lane * 8);           \
    _Pragma("unroll") for (int i = 0; i < 4; ++i)                               \
      _Pragma("unroll") for (int j = 0; j < 4; ++j)                             \
        acc[i][j] = __builtin_amdgcn_mfma_f32_16x16x32_bf16(af[i], bfr[j],      \
                                                            acc[i][j], 0, 0, 0);\
  }                                                                             \
  const int qr = quad * 4;                                                      \
  const int rl = tid >> 4, seg = (tid & 15) * 8;                                \
  _Pragma("unroll") for (int p = 0; p < 2; ++p) {                               \
    __syncthreads();                                                            \
    if ((wv >> 1) == p) {                                                       \
      _Pragma("unroll") for (int j = 0; j < 4; ++j) {                           \
        int col = wn + j * 16 + lm;                                             \
        float bvv = (bias_p) ? (bias_p)[bn + col] : 0.f;                        \
        _Pragma("unroll") for (int i = 0; i < 4; ++i)                           \
          _Pragma("unroll") for (int r = 0; r < 4; ++r)                         \
            Cs[i * 16 + qr + r][col] = f2bf(acc[i][j][r] + bvv);                \
      }                                                                         \
    }                                                                           \
    __syncthreads();                                                            \
    _Pragma("unroll") for (int pass = 0; pass < 4; ++pass) {                    \
      int row = bm + p * 64 + pass * 16 + rl;                                   \
      if (row < M)                                                              \
        *(uint4*)((outp) + (size_t)row * 512 + bn + seg) =                      \
            *(const uint4*)(&Cs[pass * 16 + rl][seg]);                          \
    }                                                                           \
  }

// single-output GEMM (embed K=256, SAGE2-Yb K=512); XCD-swizzled 1-D grid
__global__ __launch_bounds__(256) void gemm_glds(
    const unsigned short* __restrict__ Xb, int ldx, int K,
    const unsigned short* __restrict__ Wt, int ldw,
    const float* __restrict__ bias,
    unsigned short* __restrict__ outB, int M) {
  __shared__ __align__(16) unsigned char smem[17408];
  const int tid = threadIdx.x;
  const int L = blockIdx.x;
  const int xcd = L & 7, li = L >> 3;
  const int strip = xcd * 59 + (li >> 2);
  if (strip >= STRIPS) return;
  const int bm = strip * 128;
  const int bn = (li & 3) * 128;
  GEMM_BODY(Xb, ldx, Wt, ldw, bias, outB, K)
}

// dual-output GEMM: k 0..511 of Wt -> outA(+bias), k 512..1023 -> outB.
__global__ __launch_bounds__(256) void gemm_dual(
    const unsigned short* __restrict__ Xb, int ldx,
    const unsigned short* __restrict__ Wt,  // [512][1024]
    const float* __restrict__ biasA,
    unsigned short* __restrict__ outA, unsigned short* __restrict__ outBf,
    int M) {
  __shared__ __align__(16) unsigned char smem[17408];
  const int tid = threadIdx.x;
  const int L = blockIdx.x;
  const int xcd = L & 7, li = L >> 3;
  const int strip = xcd * 59 + (li >> 3);
  if (strip >= STRIPS) return;
  const int cb = li & 7;
  const int bm = strip * 128;
  const int bn = (cb & 3) * 128;
  const unsigned short* Wtb = Wt + (cb < 4 ? 0 : 512);
  const float* bias = (cb < 4) ? biasA : nullptr;
  unsigned short* outp = (cb < 4) ? outA : outBf;
  GEMM_BODY(Xb, ldx, Wtb, 1024, bias, outp, 512)
}

// ---------------------------------------------------------------------------
// Row-strip MFMA GEMM — IN-PLACE SAFE fallback (SAGE2 Ya when B3 absent).
// ---------------------------------------------------------------------------
__global__ __launch_bounds__(512) void gemm_strip(
    const unsigned short* __restrict__ Xb, int ldx,
    const unsigned short* __restrict__ Wt, int ldw,
    const float* __restrict__ bias,
    unsigned short* __restrict__ outB, int M) {
  __shared__ __align__(16) unsigned short As[64][40];
  const int tid = threadIdx.x;
  const int bm = blockIdx.x * 64;
  const int wv = tid >> 6, lane = tid & 63;
  const int lm = lane & 15, quad = lane >> 4, lk = quad * 8;
  const int cb = wv * 64;
  const int arow = tid >> 3, aseg = (tid & 7) * 4;

  f32x4 zero;
  zero[0] = 0.f; zero[1] = 0.f; zero[2] = 0.f; zero[3] = 0.f;
  f32x4 acc[4][4];
#pragma unroll
  for (int i = 0; i < 4; ++i)
#pragma unroll
    for (int j = 0; j < 4; ++j) acc[i][j] = zero;

  for (int kt = 0; kt < 512; kt += 32) {
    uint2 av = make_uint2(0, 0);
    int gr = bm + arow;
    if (gr < M) av = *(const uint2*)(Xb + (size_t)gr * ldx + kt + aseg);
    bf16x8 bfr[4];
#pragma unroll
    for (int j = 0; j < 4; ++j)
      bfr[j] = *(const bf16x8*)(Wt + (size_t)(cb + j * 16 + lm) * ldw + kt + lk);
    __syncthreads();
    *(uint2*)(&As[arow][aseg]) = av;
    __syncthreads();
    bf16x8 af[4];
#pragma unroll
    for (int i = 0; i < 4; ++i) af[i] = *(const bf16x8*)(&As[i * 16 + lm][lk]);
#pragma unroll
    for (int i = 0; i < 4; ++i)
#pragma unroll
      for (int j = 0; j < 4; ++j)
        acc[i][j] = __builtin_amdgcn_mfma_f32_16x16x32_bf16(af[i], bfr[j], acc[i][j], 0, 0, 0);
  }

  const int qr = quad * 4;
#pragma unroll
  for (int j = 0; j < 4; ++j) {
    int col = cb + j * 16 + lm;
    float bvv = bias ? bias[col] : 0.f;
#pragma unroll
    for (int i = 0; i < 4; ++i) {
      int rbase = bm + i * 16 + qr;
#pragma unroll
      for (int r = 0; r < 4; ++r) {
        int row = rbase + r;
        if (row < M) outB[(size_t)row * 512 + col] = f2bf(acc[i][j][r] + bvv);
      }
    }
  }
}

// ---------------------------------------------------------------------------
// Fused aggregation + L2 row-norm (one wave per node — R11/R13-proven).
// ---------------------------------------------------------------------------
__global__ __launch_bounds__(256) void aggr_norm(
    unsigned short* __restrict__ Ya, const unsigned short* __restrict__ Yb,
    const int* __restrict__ rowptr, const int* __restrict__ esrc,
    const float* __restrict__ invdeg, int M) {
  int d = blockIdx.x * 4 + (threadIdx.x >> 6);
  int lane = threadIdx.x & 63;
  if (d >= M) return;
  float acc[8] = {0.f, 0.f, 0.f, 0.f, 0.f, 0.f, 0.f, 0.f};
  int beg = rowptr[d], end = rowptr[d + 1];
  for (int e = beg; e < end; ++e) {
    int s = esrc[e];
    uint4 u = *(const uint4*)(Yb + (size_t)s * 512 + lane * 8);
    acc[0] += bfLo(u.x); acc[1] += bfHi(u.x);
    acc[2] += bfLo(u.y); acc[3] += bfHi(u.y);
    acc[4] += bfLo(u.z); acc[5] += bfHi(u.z);
    acc[6] += bfLo(u.w); acc[7] += bfHi(u.w);
  }
  float iv = invdeg[d];
  uint4 a = *(const uint4*)(Ya + (size_t)d * 512 + lane * 8);
  float r0 = bfLo(a.x) + iv * acc[0], r1 = bfHi(a.x) + iv * acc[1];
  float r2 = bfLo(a.y) + iv * acc[2], r3 = bfHi(a.y) + iv * acc[3];
  float r4 = bfLo(a.z) + iv * acc[4], r5 = bfHi(a.z) + iv * acc[5];
  float r6 = bfLo(a.w) + iv * acc[6], r7 = bfHi(a.w) + iv * acc[7];
  float ss = r0 * r0 + r1 * r1 + r2 * r2 + r3 * r3
           + r4 * r4 + r5 * r5 + r6 * r6 + r7 * r7;
#pragma unroll
  for (int o = 32; o; o >>= 1) ss += __shfl_xor(ss, o, 64);
  float inv = 1.0f / fmaxf(sqrtf(ss), 1e-12f);
  uint4 o4;
  o4.x = packbf(r0 * inv, r1 * inv);
  o4.y = packbf(r2 * inv, r3 * inv);
  o4.z = packbf(r4 * inv, r5 * inv);
  o4.w = packbf(r6 * inv, r7 * inv);
  *(uint4*)(Ya + (size_t)d * 512 + lane * 8) = o4;
}

// ---------------------------------------------------------------------------
// BN stats over bf16: 32 rows/block (1875 blocks — R14-proven).
// ---------------------------------------------------------------------------
__global__ __launch_bounds__(256) void bn_stats(const unsigned short* __restrict__ T,
                                                int M, float* __restrict__ sums) {
  const int t = threadIdx.x;
  int r0 = blockIdx.x * 32;
  int rend = min(r0 + 32, M);
  float s0 = 0.f, q0 = 0.f, s1 = 0.f, q1 = 0.f;
  for (int r = r0; r < rend; ++r) {
    float a = __uint_as_float((unsigned)T[(size_t)r * 512 + t] << 16);
    float b = __uint_as_float((unsigned)T[(size_t)r * 512 + t + 256] << 16);
    s0 += a; q0 += a * a; s1 += b; q1 += b * b;
  }
  atomicAdd(&sums[t], s0);
  atomicAdd(&sums[t + 256], s1);
  atomicAdd(&sums[512 + t], q0);
  atomicAdd(&sums[512 + t + 256], q1);
}

// BN apply + ReLU (+ optional residual); uint4-vectorized (8 bf16/thread).
__global__ __launch_bounds__(256) void bn_apply(const unsigned short* __restrict__ U,
                                                unsigned short* __restrict__ H,
                                                const float* __restrict__ sums,
                                                const float* __restrict__ g,
                                                const float* __restrict__ be,
                                                int M, int residual) {
  size_t i4 = (size_t)blockIdx.x * 256 + threadIdx.x;
  if (i4 >= NS / 8) return;
  int c = (int)((i4 * 8) & 511);
  float invM = 1.0f / (float)M;
  uint4 u4 = ((const uint4*)U)[i4];
  uint4 h4;
  if (residual) h4 = ((const uint4*)H)[i4];
  unsigned uin[4] = {u4.x, u4.y, u4.z, u4.w};
  unsigned hin[4] = {h4.x, h4.y, h4.z, h4.w};
  unsigned outv[4];
#pragma unroll
  for (int k = 0; k < 4; ++k) {
    int c0 = c + k * 2;
    float m0 = sums[c0] * invM, m1 = sums[c0 + 1] * invM;
    float v0 = sums[512 + c0] * invM - m0 * m0;
    float v1 = sums[512 + c0 + 1] * invM - m1 * m1;
    float k0 = rsqrtf(v0 + BN_EPS) * g[c0], k1 = rsqrtf(v1 + BN_EPS) * g[c0 + 1];
    float x0 = fmaxf((bfLo(uin[k]) - m0) * k0 + be[c0], 0.f);
    float x1 = fmaxf((bfHi(uin[k]) - m1) * k1 + be[c0 + 1], 0.f);
    if (residual) { x0 += bfLo(hin[k]); x1 += bfHi(hin[k]); }
    outv[k] = packbf(x0, x1);
  }
  uint4 o4 = make_uint4(outv[0], outv[1], outv[2], outv[3]);
  ((uint4*)H)[i4] = o4;
}

// ---------------------------------------------------------------------------
// Attention pool, sorted-batch segmented, 64 nodes/block (938 blocks).
// ---------------------------------------------------------------------------
#define NPB 64
__global__ __launch_bounds__(256) void att_pool2(const unsigned short* __restrict__ H,
                                                 const int* __restrict__ batch,
                                                 const float* __restrict__ Watt,
                                                 float* __restrict__ hg, int M) {
  __shared__ float fsh[NPB];
  __shared__ int bsh[NPB];
  const int tid = threadIdx.x;
  const int base = blockIdx.x * NPB;
  if (tid < NPB) bsh[tid] = (base + tid < M) ? batch[base + tid] : -1;
  const int wv = tid >> 6, lane = tid & 63;
  float4 wa0 = *(const float4*)(Watt + lane * 8);
  float4 wa1 = *(const float4*)(Watt + lane * 8 + 4);
  __syncthreads();
  for (int i = wv; i < NPB; i += 4) {
    int node = base + i;
    float dot = 0.f;
    if (node < M) {
      uint4 u = *(const uint4*)(H + (size_t)node * 512 + lane * 8);
      dot = bfLo(u.x) * wa0.x + bfHi(u.x) * wa0.y
          + bfLo(u.y) * wa0.z + bfHi(u.y) * wa0.w
          + bfLo(u.z) * wa1.x + bfHi(u.z) * wa1.y
          + bfLo(u.w) * wa1.z + bfHi(u.w) * wa1.w;
    }
#pragma unroll
    for (int o = 32; o; o >>= 1) dot += __shfl_xor(dot, o, 64);
    if (lane == 0) fsh[i] = 0.5f * (1.0f + 1.0f / (1.0f + expf(-dot)));
  }
  __syncthreads();
  float a0 = 0.f, a1 = 0.f;
  int cur = bsh[0];
  for (int i = 0; i < NPB; ++i) {
    int node = base + i;
    if (node >= M) break;
    int b = bsh[i];
    if (b != cur) {
      atomicAdd(&hg[(size_t)cur * 512 + tid * 2], a0);
      atomicAdd(&hg[(size_t)cur * 512 + tid * 2 + 1], a1);
      a0 = a1 = 0.f;
      cur = b;
    }
    unsigned u = *(const unsigned*)(H + (size_t)node * 512 + tid * 2);
    float f = fsh[i];
    a0 += bfLo(u) * f;
    a1 += bfHi(u) * f;
  }
  if (cur >= 0) {
    atomicAdd(&hg[(size_t)cur * 512 + tid * 2], a0);
    atomicAdd(&hg[(size_t)cur * 512 + tid * 2 + 1], a1);
  }
}

// ---------------------------------------------------------------------------
// Readout: out[g, n] = (hg[g]/bcnt[g]) . Wread[:, n]
// ---------------------------------------------------------------------------
__global__ __launch_bounds__(256) void readout(const float* __restrict__ hg,
                                               const float* __restrict__ bcnt,
                                               const float* __restrict__ Wr,
                                               float* __restrict__ out) {
  __shared__ float sh[HID];
  int g = blockIdx.x;
  int n = blockIdx.y * 256 + threadIdx.x;
  float inv = 1.0f / fmaxf(bcnt[g], 1.0f);
  for (int k = threadIdx.x; k < HID; k += 256) sh[k] = hg[(size_t)g * HID + k] * inv;
  __syncthreads();
  if (n < NCLS) {
    float acc = 0.f;
    for (int k = 0; k < HID; ++k) acc += sh[k] * Wr[(size_t)k * NCLS + n];
    out[(size_t)g * NCLS + n] = acc;
  }
}

// ---------------------------------------------------------------------------
extern "C" void kernel_launch(void* const* d_in, const int* in_sizes, int n_in,
                              void* d_out, int out_size, void* d_ws, size_t ws_size,
                              hipStream_t stream) {
  const float* x       = (const float*)d_in[0];
  const int*   ei      = (const int*)d_in[1];
  const int*   batch   = (const int*)d_in[2];
  const float* W_embed = (const float*)d_in[3];
  const float* W1      = (const float*)d_in[4];
  const float* b1      = (const float*)d_in[5];
  const float* g1      = (const float*)d_in[6];
  const float* be1     = (const float*)d_in[7];
  const float* W2      = (const float*)d_in[8];
  const float* b2      = (const float*)d_in[9];
  const float* g2      = (const float*)d_in[10];
  const float* be2     = (const float*)d_in[11];
  const float* Watt    = (const float*)d_in[12];
  const float* Wread   = (const float*)d_in[13];
  float* out = (float*)d_out;

  const int* srcIdx = ei;
  const int* dstIdx = ei + N_EDGES;

  char* p = (char*)d_ws;
  unsigned short* B0 = (unsigned short*)p; p += NS * 2;   // h (residual)
  unsigned short* B1 = (unsigned short*)p; p += NS * 2;   // Ya / T / x_bf16
  unsigned short* B2 = (unsigned short*)p; p += NS * 2;   // Yb
  unsigned short* WtE = (unsigned short*)p; p += (size_t)512 * 256 * 2;
  unsigned short* Wt1 = (unsigned short*)p; p += (size_t)3 * 512 * 1024 * 2;
  unsigned short* Wt2 = (unsigned short*)p; p += (size_t)3 * 512 * 1024 * 2;
  float* hg     = (float*)p; p += (size_t)N_GRAPH * HID * 4;
  float* sums   = (float*)p; p += 1024 * 4;
  float* invdeg = (float*)p; p += (size_t)N_NODES * 4;
  float* bcnt   = (float*)p; p += 256;
  int* deg      = (int*)p;   p += (size_t)N_NODES * 4;
  int* fillc    = (int*)p;   p += (size_t)N_NODES * 4;
  int* esrc     = (int*)p;   p += (size_t)N_EDGES * 4;
  int* rowptr   = (int*)p;   p += (size_t)(N_NODES + 1) * 4;
  int* bsum     = (int*)p;   p += (size_t)NB * 4;
  size_t need = (size_t)(p - (char*)d_ws);
  if (ws_size < need) {
    write_sentinel<<<1, 1, 0, stream>>>(out, (float)need);
    return;
  }
  // optional 4th activation buffer -> SAGE2 also runs as a single gemm_dual
  unsigned short* B3 = nullptr;
  if (ws_size >= need + NS * 2) B3 = (unsigned short*)((char*)d_ws + need);

  // ---- weight prep (fp32 -> bf16, transposed [N][K]); layer-batched
  wtrans<<<dim3(8, 16, 1), 256, 0, stream>>>(W_embed, WtE, 256, 512, 0, 0);
  wtrans<<<dim3(32, 16, 3), 256, 0, stream>>>(W1, Wt1, 1024, 512,
                                              (size_t)1024 * 512, (size_t)512 * 1024);
  wtrans<<<dim3(32, 16, 3), 256, 0, stream>>>(W2, Wt2, 1024, 512,
                                              (size_t)1024 * 512, (size_t)512 * 1024);

  // ---- CSR build (parallel scan)
  hipMemsetAsync(deg, 0, N_NODES * sizeof(int), stream);
  hipMemsetAsync(fillc, 0, N_NODES * sizeof(int), stream);
  count_deg<<<(N_EDGES + 255) / 256, 256, 0, stream>>>(dstIdx, deg, N_EDGES);
  make_invdeg<<<(N_NODES + 255) / 256, 256, 0, stream>>>(deg, invdeg, N_NODES);
  scan_part<<<NB, 256, 0, stream>>>(deg, bsum, N_NODES);
  scan_bsums<<<1, 256, 0, stream>>>(bsum, NB);
  scan_final<<<NB, 256, 0, stream>>>(deg, bsum, rowptr, N_NODES);
  fill_csr<<<(N_EDGES + 255) / 256, 256, 0, stream>>>(srcIdx, dstIdx, rowptr, fillc,
                                                      esrc, N_EDGES);

  const int g1grid = 8 * 59 * 4;  // single-output GEMM grid (1888)
  const int g2grid = 8 * 59 * 8;  // dual-output GEMM grid (3776)
  const int sgrid  = (N_NODES + 63) / 64;
  const int ngrid  = (N_NODES + 3) / 4;     // aggr_norm: one wave per node
  const int bgrid  = (N_NODES + 31) / 32;   // bn_stats: 32 rows/block
  const int egrid  = (int)((NS / 8 + 255) / 256);

  // ---- embed: x -> bf16 (B1), then h = x @ W_embed -> B0
  cvt_bf16<<<(int)(((size_t)N_NODES * 64 + 255) / 256), 256, 0, stream>>>(
      x, B1, (long)N_NODES * 64);
  gemm_glds<<<g1grid, 256, 0, stream>>>(B1, 256, 256, WtE, 256, nullptr, B0, N_NODES);

  for (int l = 0; l < 3; ++l) {
    const unsigned short* Wt1l = Wt1 + (size_t)l * 512 * 1024;
    const unsigned short* Wt2l = Wt2 + (size_t)l * 512 * 1024;
    // ---- SAGE 1: B1 = Ya+bias, B2 = Yb (one fused launch)
    gemm_dual<<<g2grid, 256, 0, stream>>>(B0, 512, Wt1l, b1 + l * 512, B1, B2, N_NODES);
    aggr_norm<<<ngrid, 256, 0, stream>>>(B1, B2, rowptr, esrc, invdeg, N_NODES);
    hipMemsetAsync(sums, 0, 1024 * sizeof(float), stream);
    bn_stats<<<bgrid, 256, 0, stream>>>(B1, N_NODES, sums);
    bn_apply<<<egrid, 256, 0, stream>>>(B1, B1, sums, g1 + l * 512,
                                        be1 + l * 512, N_NODES, 0);
    // ---- SAGE 2 + residual
    unsigned short* Ya2 = B3 ? B3 : B1;
    if (B3) {
      gemm_dual<<<g2grid, 256, 0, stream>>>(B1, 512, Wt2l, b2 + l * 512, B3, B2,
                                            N_NODES);
    } else {
      gemm_glds<<<g1grid, 256, 0, stream>>>(B1, 512, 512, Wt2l + 512, 1024,
                                            nullptr, B2, N_NODES);       // Yb
      gemm_strip<<<sgrid, 512, 0, stream>>>(B1, 512, Wt2l, 1024,
                                            b2 + l * 512, B1, N_NODES);  // Ya in-place
    }
    aggr_norm<<<ngrid, 256, 0, stream>>>(Ya2, B2, rowptr, esrc, invdeg, N_NODES);
    hipMemsetAsync(sums, 0, 1024 * sizeof(float), stream);
    bn_stats<<<bgrid, 256, 0, stream>>>(Ya2, N_NODES, sums);
    bn_apply<<<egrid, 256, 0, stream>>>(Ya2, B0, sums, g2 + l * 512,
                                        be2 + l * 512, N_NODES, 1);
  }

  // ---- pooling + readout
  hipMemsetAsync(hg, 0, (size_t)N_GRAPH * HID * sizeof(float), stream);
  hipMemsetAsync(bcnt, 0, N_GRAPH * sizeof(float), stream);
  bcount<<<NB, 256, 0, stream>>>(batch, bcnt, N_NODES);
  att_pool2<<<(N_NODES + NPB - 1) / NPB, 256, 0, stream>>>(B0, batch, Watt, hg, N_NODES);
  readout<<<dim3(N_GRAPH, 4), 256, 0, stream>>>(hg, bcnt, Wread, out);
}

// Round 16
// 1943.051 us; speedup vs baseline: 1.2457x; 1.0105x over previous
//
#include <hip/hip_runtime.h>
#include <math.h>

#define N_NODES 60000
#define N_EDGES 360000
#define N_GRAPH 64
#define HID 512
#define NCLS 1000
#define BN_EPS 1e-5f
#define NS ((size_t)N_NODES * HID)
#define NB 235      // (N_NODES + 255) / 256
#define STRIPS 469  // ceil(60000/128)

typedef __bf16 bf16x8 __attribute__((ext_vector_type(8)));
typedef float f32x4 __attribute__((ext_vector_type(4)));

static __device__ __forceinline__ unsigned short f2bf(float f) {
  unsigned u = __float_as_uint(f);
  unsigned r = (u + 0x7fffu + ((u >> 16) & 1u)) >> 16;  // RNE
  return (unsigned short)r;
}
static __device__ __forceinline__ float bfLo(unsigned u) { return __uint_as_float(u << 16); }
static __device__ __forceinline__ float bfHi(unsigned u) { return __uint_as_float(u & 0xffff0000u); }
static __device__ __forceinline__ unsigned packbf(float a, float b) {
  return (unsigned)f2bf(a) | ((unsigned)f2bf(b) << 16);
}

__global__ void write_sentinel(float* out, float v) { out[0] = v; }

// fp32 -> bf16 elementwise convert (embed input), 4 elems/thread
__global__ __launch_bounds__(256) void cvt_bf16(const float* __restrict__ X,
                                                unsigned short* __restrict__ Y,
                                                long n4) {
  long i = (long)blockIdx.x * 256 + threadIdx.x;
  if (i >= n4) return;
  float4 f = *(const float4*)(X + i * 4);
  uint2 o;
  o.x = packbf(f.x, f.y);
  o.y = packbf(f.z, f.w);
  *(uint2*)(Y + i * 4) = o;
}

// ---------------------------------------------------------------------------
// Weight fp32 -> bf16 transpose: Wt[n][k] = bf16(W[k][n]).  32x32 tiles.
// blockIdx.z = layer (batched).
// ---------------------------------------------------------------------------
__global__ __launch_bounds__(256) void wtrans(const float* __restrict__ W,
                                              unsigned short* __restrict__ Wt,
                                              int K, int N,
                                              size_t strideW, size_t strideWt) {
  __shared__ float sh[32][33];
  W += (size_t)blockIdx.z * strideW;
  Wt += (size_t)blockIdx.z * strideWt;
  int kt = blockIdx.x * 32, nt = blockIdx.y * 32;
  int tx = threadIdx.x & 31, ty = threadIdx.x >> 5;  // ty 0..7
#pragma unroll
  for (int i = 0; i < 4; ++i)
    sh[ty + i * 8][tx] = W[(size_t)(kt + ty + i * 8) * N + nt + tx];
  __syncthreads();
#pragma unroll
  for (int i = 0; i < 4; ++i)
    Wt[(size_t)(nt + ty + i * 8) * K + kt + tx] = f2bf(sh[tx][ty + i * 8]);
}

// ---------------------------------------------------------------------------
// Degree / CSR build
// ---------------------------------------------------------------------------
__global__ __launch_bounds__(256) void count_deg(const int* __restrict__ dst,
                                                 int* __restrict__ deg, int E) {
  int e = blockIdx.x * 256 + threadIdx.x;
  if (e < E) atomicAdd(&deg[dst[e]], 1);
}

__global__ __launch_bounds__(256) void make_invdeg(const int* __restrict__ deg,
                                                   float* __restrict__ inv, int n) {
  int i = blockIdx.x * 256 + threadIdx.x;
  if (i < n) inv[i] = 1.0f / fmaxf((float)deg[i], 1.0f);
}

__global__ __launch_bounds__(256) void scan_part(const int* __restrict__ deg,
                                                 int* __restrict__ bsum, int n) {
  __shared__ int sh[256];
  int i = blockIdx.x * 256 + threadIdx.x;
  sh[threadIdx.x] = (i < n) ? deg[i] : 0;
  __syncthreads();
  for (int off = 128; off; off >>= 1) {
    if (threadIdx.x < off) sh[threadIdx.x] += sh[threadIdx.x + off];
    __syncthreads();
  }
  if (threadIdx.x == 0) bsum[blockIdx.x] = sh[0];
}

__global__ __launch_bounds__(256) void scan_bsums(int* __restrict__ bsum, int nb) {
  __shared__ int sh[256];
  int t = threadIdx.x;
  int v = (t < nb) ? bsum[t] : 0;
  sh[t] = v;
  __syncthreads();
  for (int off = 1; off < 256; off <<= 1) {
    int u = (t >= off) ? sh[t - off] : 0;
    __syncthreads();
    sh[t] += u;
    __syncthreads();
  }
  if (t < nb) bsum[t] = sh[t] - v;  // exclusive
}

__global__ __launch_bounds__(256) void scan_final(const int* __restrict__ deg,
                                                  const int* __restrict__ bsum,
                                                  int* __restrict__ rowptr, int n) {
  __shared__ int sh[256];
  int t = threadIdx.x;
  int i = blockIdx.x * 256 + t;
  int v = (i < n) ? deg[i] : 0;
  sh[t] = v;
  __syncthreads();
  for (int off = 1; off < 256; off <<= 1) {
    int u = (t >= off) ? sh[t - off] : 0;
    __syncthreads();
    sh[t] += u;
    __syncthreads();
  }
  if (i < n) rowptr[i + 1] = bsum[blockIdx.x] + sh[t];
  if (i == 0) rowptr[0] = 0;
}

__global__ __launch_bounds__(256) void fill_csr(const int* __restrict__ src,
                                                const int* __restrict__ dst,
                                                const int* __restrict__ rowptr,
                                                int* __restrict__ fillc,
                                                int* __restrict__ esrc, int E) {
  int e = blockIdx.x * 256 + threadIdx.x;
  if (e < E) {
    int d = dst[e];
    int pos = rowptr[d] + atomicAdd(&fillc[d], 1);
    esrc[pos] = src[e];
  }
}

// LDS-histogram batch count
__global__ __launch_bounds__(256) void bcount(const int* __restrict__ batch,
                                              float* __restrict__ bcnt, int n) {
  __shared__ int h[N_GRAPH];
  if (threadIdx.x < N_GRAPH) h[threadIdx.x] = 0;
  __syncthreads();
  int i = blockIdx.x * 256 + threadIdx.x;
  if (i < n) atomicAdd(&h[batch[i]], 1);
  __syncthreads();
  if (threadIdx.x < N_GRAPH && h[threadIdx.x])
    atomicAdd(&bcnt[threadIdx.x], (float)h[threadIdx.x]);
}

// ---------------------------------------------------------------------------
// GEMM block body v3: double-buffered glds prefetch, ONE barrier per k-tile.
// smem = 32768B: buf0 As@0 Bs@8192, buf1 As@16384 Bs@24576 (halfs: 8192/buf).
// Iter t: barrier (drains tile-t loads, which overlapped compute t-1);
//         issue tile t+1 into other buffer (safe: that buffer's readers all
//         passed this barrier); compute tile t.
// Cs (64x136 halfs, 17408B) aliases buf0/1 — epilogue barrier separates.
// ---------------------------------------------------------------------------
#define GEMM_STAGE(Xb, ldx, Wtb, ldw, ktv, sel)                                 \
  {                                                                             \
    unsigned short* dA = base + (sel) * 8192;                                   \
    unsigned short* dB = dA + 4096;                                             \
    _Pragma("unroll") for (int r = 0; r < 2; ++r) {                             \
      int chunk = wv + r * 4;                                                   \
      int row = chunk * 16 + grow;                                              \
      const unsigned short* ga = (Xb) + (size_t)(bm + row) * (ldx) + (ktv) + gseg; \
      const unsigned short* gb = (Wtb) + (size_t)(bn + row) * (ldw) + (ktv) + gseg;\
      __builtin_amdgcn_global_load_lds(                                         \
          (const __attribute__((address_space(1))) unsigned int*)ga,            \
          (__attribute__((address_space(3))) unsigned int*)(dA + chunk * 512),  \
          16, 0, 0);                                                            \
      __builtin_amdgcn_global_load_lds(                                         \
          (const __attribute__((address_space(1))) unsigned int*)gb,            \
          (__attribute__((address_space(3))) unsigned int*)(dB + chunk * 512),  \
          16, 0, 0);                                                            \
    }                                                                           \
  }

#define GEMM_BODY(Xb, ldx, Wtb, ldw, bias_p, outp, KDIM)                        \
  unsigned short* base = (unsigned short*)smem;                                 \
  typedef unsigned short CsRow[136];                                            \
  CsRow* Cs = (CsRow*)smem;                                                     \
  const int wv = tid >> 6, lane = tid & 63;                                     \
  const int wm = (wv >> 1) * 64, wn = (wv & 1) * 64;                            \
  const int lm = lane & 15, quad = lane >> 4;                                   \
  const int grow = lane & 15, gseg = (lane >> 4) * 8;                           \
  f32x4 zero; zero[0] = 0.f; zero[1] = 0.f; zero[2] = 0.f; zero[3] = 0.f;       \
  f32x4 acc[4][4];                                                              \
  _Pragma("unroll") for (int i = 0; i < 4; ++i)                                 \
    _Pragma("unroll") for (int j = 0; j < 4; ++j) acc[i][j] = zero;             \
  const int T = (KDIM) / 32;                                                    \
  GEMM_STAGE(Xb, ldx, Wtb, ldw, 0, 0)                                           \
  for (int t = 0; t < T; ++t) {                                                 \
    __syncthreads();                                                            \
    if (t + 1 < T) GEMM_STAGE(Xb, ldx, Wtb, ldw, (t + 1) * 32, (t + 1) & 1)     \
    const unsigned short* AsC = base + (t & 1) * 8192;                          \
    const unsigned short* BsC = AsC + 4096;                                     \
    bf16x8 af[4], bfr[4];                                                       \
    _Pragma("unroll") for (int i = 0; i < 4; ++i)                               \
      af[i] = *(const bf16x8*)(AsC + (wm / 16 + i) * 512 + lane * 8);           \
    _Pragma("unroll") for (int j = 0; j < 4; ++j)                               \
      bfr[j] = *(const bf16x8*)(BsC + (wn / 16 + j) * 512 + lane * 8);          \
    _Pragma("unroll") for (int i = 0; i < 4; ++i)                               \
      _Pragma("unroll") for (int j = 0; j < 4; ++j)                             \
        acc[i][j] = __builtin_amdgcn_mfma_f32_16x16x32_bf16(af[i], bfr[j],      \
                                                            acc[i][j], 0, 0, 0);\
  }                                                                             \
  const int qr = quad * 4;                                                      \
  const int rl = tid >> 4, seg = (tid & 15) * 8;                                \
  _Pragma("unroll") for (int p = 0; p < 2; ++p) {                               \
    __syncthreads();                                                            \
    if ((wv >> 1) == p) {                                                       \
      _Pragma("unroll") for (int j = 0; j < 4; ++j) {                           \
        int col = wn + j * 16 + lm;                                             \
        float bvv = (bias_p) ? (bias_p)[bn + col] : 0.f;                        \
        _Pragma("unroll") for (int i = 0; i < 4; ++i)                           \
          _Pragma("unroll") for (int r = 0; r < 4; ++r)                         \
            Cs[i * 16 + qr + r][col] = f2bf(acc[i][j][r] + bvv);                \
      }                                                                         \
    }                                                                           \
    __syncthreads();                                                            \
    _Pragma("unroll") for (int pass = 0; pass < 4; ++pass) {                    \
      int row = bm + p * 64 + pass * 16 + rl;                                   \
      if (row < M)                                                              \
        *(uint4*)((outp) + (size_t)row * 512 + bn + seg) =                      \
            *(const uint4*)(&Cs[pass * 16 + rl][seg]);                          \
    }                                                                           \
  }

// single-output GEMM (embed K=256, SAGE2-Yb K=512); XCD-swizzled 1-D grid
__global__ __launch_bounds__(256) void gemm_glds(
    const unsigned short* __restrict__ Xb, int ldx, int K,
    const unsigned short* __restrict__ Wt, int ldw,
    const float* __restrict__ bias,
    unsigned short* __restrict__ outB, int M) {
  __shared__ __align__(16) unsigned char smem[32768];
  const int tid = threadIdx.x;
  const int L = blockIdx.x;
  const int xcd = L & 7, li = L >> 3;
  const int strip = xcd * 59 + (li >> 2);
  if (strip >= STRIPS) return;
  const int bm = strip * 128;
  const int bn = (li & 3) * 128;
  GEMM_BODY(Xb, ldx, Wt, ldw, bias, outB, K)
}

// dual-output GEMM: k 0..511 of Wt -> outA(+bias), k 512..1023 -> outB.
__global__ __launch_bounds__(256) void gemm_dual(
    const unsigned short* __restrict__ Xb, int ldx,
    const unsigned short* __restrict__ Wt,  // [512][1024]
    const float* __restrict__ biasA,
    unsigned short* __restrict__ outA, unsigned short* __restrict__ outBf,
    int M) {
  __shared__ __align__(16) unsigned char smem[32768];
  const int tid = threadIdx.x;
  const int L = blockIdx.x;
  const int xcd = L & 7, li = L >> 3;
  const int strip = xcd * 59 + (li >> 3);
  if (strip >= STRIPS) return;
  const int cb = li & 7;
  const int bm = strip * 128;
  const int bn = (cb & 3) * 128;
  const unsigned short* Wtb = Wt + (cb < 4 ? 0 : 512);
  const float* bias = (cb < 4) ? biasA : nullptr;
  unsigned short* outp = (cb < 4) ? outA : outBf;
  GEMM_BODY(Xb, ldx, Wtb, 1024, bias, outp, 512)
}

// ---------------------------------------------------------------------------
// Row-strip MFMA GEMM — IN-PLACE SAFE fallback (SAGE2 Ya when B3 absent).
// ---------------------------------------------------------------------------
__global__ __launch_bounds__(512) void gemm_strip(
    const unsigned short* __restrict__ Xb, int ldx,
    const unsigned short* __restrict__ Wt, int ldw,
    const float* __restrict__ bias,
    unsigned short* __restrict__ outB, int M) {
  __shared__ __align__(16) unsigned short As[64][40];
  const int tid = threadIdx.x;
  const int bm = blockIdx.x * 64;
  const int wv = tid >> 6, lane = tid & 63;
  const int lm = lane & 15, quad = lane >> 4, lk = quad * 8;
  const int cb = wv * 64;
  const int arow = tid >> 3, aseg = (tid & 7) * 4;

  f32x4 zero;
  zero[0] = 0.f; zero[1] = 0.f; zero[2] = 0.f; zero[3] = 0.f;
  f32x4 acc[4][4];
#pragma unroll
  for (int i = 0; i < 4; ++i)
#pragma unroll
    for (int j = 0; j < 4; ++j) acc[i][j] = zero;

  for (int kt = 0; kt < 512; kt += 32) {
    uint2 av = make_uint2(0, 0);
    int gr = bm + arow;
    if (gr < M) av = *(const uint2*)(Xb + (size_t)gr * ldx + kt + aseg);
    bf16x8 bfr[4];
#pragma unroll
    for (int j = 0; j < 4; ++j)
      bfr[j] = *(const bf16x8*)(Wt + (size_t)(cb + j * 16 + lm) * ldw + kt + lk);
    __syncthreads();
    *(uint2*)(&As[arow][aseg]) = av;
    __syncthreads();
    bf16x8 af[4];
#pragma unroll
    for (int i = 0; i < 4; ++i) af[i] = *(const bf16x8*)(&As[i * 16 + lm][lk]);
#pragma unroll
    for (int i = 0; i < 4; ++i)
#pragma unroll
      for (int j = 0; j < 4; ++j)
        acc[i][j] = __builtin_amdgcn_mfma_f32_16x16x32_bf16(af[i], bfr[j], acc[i][j], 0, 0, 0);
  }

  const int qr = quad * 4;
#pragma unroll
  for (int j = 0; j < 4; ++j) {
    int col = cb + j * 16 + lm;
    float bvv = bias ? bias[col] : 0.f;
#pragma unroll
    for (int i = 0; i < 4; ++i) {
      int rbase = bm + i * 16 + qr;
#pragma unroll
      for (int r = 0; r < 4; ++r) {
        int row = rbase + r;
        if (row < M) outB[(size_t)row * 512 + col] = f2bf(acc[i][j][r] + bvv);
      }
    }
  }
}

// ---------------------------------------------------------------------------
// Fused aggregation + L2 row-norm (one wave per node). 4-edge batched gather:
// 4 independent row loads in flight per iter (was 1 dependent chain).
// ---------------------------------------------------------------------------
__global__ __launch_bounds__(256) void aggr_norm(
    unsigned short* __restrict__ Ya, const unsigned short* __restrict__ Yb,
    const int* __restrict__ rowptr, const int* __restrict__ esrc,
    const float* __restrict__ invdeg, int M) {
  int d = blockIdx.x * 4 + (threadIdx.x >> 6);
  int lane = threadIdx.x & 63;
  if (d >= M) return;
  float acc[8] = {0.f, 0.f, 0.f, 0.f, 0.f, 0.f, 0.f, 0.f};
  int beg = rowptr[d], end = rowptr[d + 1];
  int e = beg;
  for (; e + 4 <= end; e += 4) {
    int s0 = esrc[e], s1 = esrc[e + 1], s2 = esrc[e + 2], s3 = esrc[e + 3];
    uint4 u0 = *(const uint4*)(Yb + (size_t)s0 * 512 + lane * 8);
    uint4 u1 = *(const uint4*)(Yb + (size_t)s1 * 512 + lane * 8);
    uint4 u2 = *(const uint4*)(Yb + (size_t)s2 * 512 + lane * 8);
    uint4 u3 = *(const uint4*)(Yb + (size_t)s3 * 512 + lane * 8);
    acc[0] += bfLo(u0.x) + bfLo(u1.x) + bfLo(u2.x) + bfLo(u3.x);
    acc[1] += bfHi(u0.x) + bfHi(u1.x) + bfHi(u2.x) + bfHi(u3.x);
    acc[2] += bfLo(u0.y) + bfLo(u1.y) + bfLo(u2.y) + bfLo(u3.y);
    acc[3] += bfHi(u0.y) + bfHi(u1.y) + bfHi(u2.y) + bfHi(u3.y);
    acc[4] += bfLo(u0.z) + bfLo(u1.z) + bfLo(u2.z) + bfLo(u3.z);
    acc[5] += bfHi(u0.z) + bfHi(u1.z) + bfHi(u2.z) + bfHi(u3.z);
    acc[6] += bfLo(u0.w) + bfLo(u1.w) + bfLo(u2.w) + bfLo(u3.w);
    acc[7] += bfHi(u0.w) + bfHi(u1.w) + bfHi(u2.w) + bfHi(u3.w);
  }
  for (; e < end; ++e) {
    int s = esrc[e];
    uint4 u = *(const uint4*)(Yb + (size_t)s * 512 + lane * 8);
    acc[0] += bfLo(u.x); acc[1] += bfHi(u.x);
    acc[2] += bfLo(u.y); acc[3] += bfHi(u.y);
    acc[4] += bfLo(u.z); acc[5] += bfHi(u.z);
    acc[6] += bfLo(u.w); acc[7] += bfHi(u.w);
  }
  float iv = invdeg[d];
  uint4 a = *(const uint4*)(Ya + (size_t)d * 512 + lane * 8);
  float r0 = bfLo(a.x) + iv * acc[0], r1 = bfHi(a.x) + iv * acc[1];
  float r2 = bfLo(a.y) + iv * acc[2], r3 = bfHi(a.y) + iv * acc[3];
  float r4 = bfLo(a.z) + iv * acc[4], r5 = bfHi(a.z) + iv * acc[5];
  float r6 = bfLo(a.w) + iv * acc[6], r7 = bfHi(a.w) + iv * acc[7];
  float ss = r0 * r0 + r1 * r1 + r2 * r2 + r3 * r3
           + r4 * r4 + r5 * r5 + r6 * r6 + r7 * r7;
#pragma unroll
  for (int o = 32; o; o >>= 1) ss += __shfl_xor(ss, o, 64);
  float inv = 1.0f / fmaxf(sqrtf(ss), 1e-12f);
  uint4 o4;
  o4.x = packbf(r0 * inv, r1 * inv);
  o4.y = packbf(r2 * inv, r3 * inv);
  o4.z = packbf(r4 * inv, r5 * inv);
  o4.w = packbf(r6 * inv, r7 * inv);
  *(uint4*)(Ya + (size_t)d * 512 + lane * 8) = o4;
}

// ---------------------------------------------------------------------------
// BN stats over bf16: 32 rows/block (1875 blocks — R14-proven).
// ---------------------------------------------------------------------------
__global__ __launch_bounds__(256) void bn_stats(const unsigned short* __restrict__ T,
                                                int M, float* __restrict__ sums) {
  const int t = threadIdx.x;
  int r0 = blockIdx.x * 32;
  int rend = min(r0 + 32, M);
  float s0 = 0.f, q0 = 0.f, s1 = 0.f, q1 = 0.f;
  for (int r = r0; r < rend; ++r) {
    float a = __uint_as_float((unsigned)T[(size_t)r * 512 + t] << 16);
    float b = __uint_as_float((unsigned)T[(size_t)r * 512 + t + 256] << 16);
    s0 += a; q0 += a * a; s1 += b; q1 += b * b;
  }
  atomicAdd(&sums[t], s0);
  atomicAdd(&sums[t + 256], s1);
  atomicAdd(&sums[512 + t], q0);
  atomicAdd(&sums[512 + t + 256], q1);
}

// BN apply + ReLU (+ optional residual); uint4-vectorized (8 bf16/thread).
__global__ __launch_bounds__(256) void bn_apply(const unsigned short* __restrict__ U,
                                                unsigned short* __restrict__ H,
                                                const float* __restrict__ sums,
                                                const float* __restrict__ g,
                                                const float* __restrict__ be,
                                                int M, int residual) {
  size_t i4 = (size_t)blockIdx.x * 256 + threadIdx.x;
  if (i4 >= NS / 8) return;
  int c = (int)((i4 * 8) & 511);
  float invM = 1.0f / (float)M;
  uint4 u4 = ((const uint4*)U)[i4];
  uint4 h4;
  if (residual) h4 = ((const uint4*)H)[i4];
  unsigned uin[4] = {u4.x, u4.y, u4.z, u4.w};
  unsigned hin[4] = {h4.x, h4.y, h4.z, h4.w};
  unsigned outv[4];
#pragma unroll
  for (int k = 0; k < 4; ++k) {
    int c0 = c + k * 2;
    float m0 = sums[c0] * invM, m1 = sums[c0 + 1] * invM;
    float v0 = sums[512 + c0] * invM - m0 * m0;
    float v1 = sums[512 + c0 + 1] * invM - m1 * m1;
    float k0 = rsqrtf(v0 + BN_EPS) * g[c0], k1 = rsqrtf(v1 + BN_EPS) * g[c0 + 1];
    float x0 = fmaxf((bfLo(uin[k]) - m0) * k0 + be[c0], 0.f);
    float x1 = fmaxf((bfHi(uin[k]) - m1) * k1 + be[c0 + 1], 0.f);
    if (residual) { x0 += bfLo(hin[k]); x1 += bfHi(hin[k]); }
    outv[k] = packbf(x0, x1);
  }
  uint4 o4 = make_uint4(outv[0], outv[1], outv[2], outv[3]);
  ((uint4*)H)[i4] = o4;
}

// ---------------------------------------------------------------------------
// Attention pool, sorted-batch segmented, 64 nodes/block (938 blocks).
// ---------------------------------------------------------------------------
#define NPB 64
__global__ __launch_bounds__(256) void att_pool2(const unsigned short* __restrict__ H,
                                                 const int* __restrict__ batch,
                                                 const float* __restrict__ Watt,
                                                 float* __restrict__ hg, int M) {
  __shared__ float fsh[NPB];
  __shared__ int bsh[NPB];
  const int tid = threadIdx.x;
  const int base = blockIdx.x * NPB;
  if (tid < NPB) bsh[tid] = (base + tid < M) ? batch[base + tid] : -1;
  const int wv = tid >> 6, lane = tid & 63;
  float4 wa0 = *(const float4*)(Watt + lane * 8);
  float4 wa1 = *(const float4*)(Watt + lane * 8 + 4);
  __syncthreads();
  for (int i = wv; i < NPB; i += 4) {
    int node = base + i;
    float dot = 0.f;
    if (node < M) {
      uint4 u = *(const uint4*)(H + (size_t)node * 512 + lane * 8);
      dot = bfLo(u.x) * wa0.x + bfHi(u.x) * wa0.y
          + bfLo(u.y) * wa0.z + bfHi(u.y) * wa0.w
          + bfLo(u.z) * wa1.x + bfHi(u.z) * wa1.y
          + bfLo(u.w) * wa1.z + bfHi(u.w) * wa1.w;
    }
#pragma unroll
    for (int o = 32; o; o >>= 1) dot += __shfl_xor(dot, o, 64);
    if (lane == 0) fsh[i] = 0.5f * (1.0f + 1.0f / (1.0f + expf(-dot)));
  }
  __syncthreads();
  float a0 = 0.f, a1 = 0.f;
  int cur = bsh[0];
  for (int i = 0; i < NPB; ++i) {
    int node = base + i;
    if (node >= M) break;
    int b = bsh[i];
    if (b != cur) {
      atomicAdd(&hg[(size_t)cur * 512 + tid * 2], a0);
      atomicAdd(&hg[(size_t)cur * 512 + tid * 2 + 1], a1);
      a0 = a1 = 0.f;
      cur = b;
    }
    unsigned u = *(const unsigned*)(H + (size_t)node * 512 + tid * 2);
    float f = fsh[i];
    a0 += bfLo(u) * f;
    a1 += bfHi(u) * f;
  }
  if (cur >= 0) {
    atomicAdd(&hg[(size_t)cur * 512 + tid * 2], a0);
    atomicAdd(&hg[(size_t)cur * 512 + tid * 2 + 1], a1);
  }
}

// ---------------------------------------------------------------------------
// Readout: out[g, n] = (hg[g]/bcnt[g]) . Wread[:, n]
// ---------------------------------------------------------------------------
__global__ __launch_bounds__(256) void readout(const float* __restrict__ hg,
                                               const float* __restrict__ bcnt,
                                               const float* __restrict__ Wr,
                                               float* __restrict__ out) {
  __shared__ float sh[HID];
  int g = blockIdx.x;
  int n = blockIdx.y * 256 + threadIdx.x;
  float inv = 1.0f / fmaxf(bcnt[g], 1.0f);
  for (int k = threadIdx.x; k < HID; k += 256) sh[k] = hg[(size_t)g * HID + k] * inv;
  __syncthreads();
  if (n < NCLS) {
    float acc = 0.f;
    for (int k = 0; k < HID; ++k) acc += sh[k] * Wr[(size_t)k * NCLS + n];
    out[(size_t)g * NCLS + n] = acc;
  }
}

// ---------------------------------------------------------------------------
extern "C" void kernel_launch(void* const* d_in, const int* in_sizes, int n_in,
                              void* d_out, int out_size, void* d_ws, size_t ws_size,
                              hipStream_t stream) {
  const float* x       = (const float*)d_in[0];
  const int*   ei      = (const int*)d_in[1];
  const int*   batch   = (const int*)d_in[2];
  const float* W_embed = (const float*)d_in[3];
  const float* W1      = (const float*)d_in[4];
  const float* b1      = (const float*)d_in[5];
  const float* g1      = (const float*)d_in[6];
  const float* be1     = (const float*)d_in[7];
  const float* W2      = (const float*)d_in[8];
  const float* b2      = (const float*)d_in[9];
  const float* g2      = (const float*)d_in[10];
  const float* be2     = (const float*)d_in[11];
  const float* Watt    = (const float*)d_in[12];
  const float* Wread   = (const float*)d_in[13];
  float* out = (float*)d_out;

  const int* srcIdx = ei;
  const int* dstIdx = ei + N_EDGES;

  char* p = (char*)d_ws;
  unsigned short* B0 = (unsigned short*)p; p += NS * 2;   // h (residual)
  unsigned short* B1 = (unsigned short*)p; p += NS * 2;   // Ya / T / x_bf16
  unsigned short* B2 = (unsigned short*)p; p += NS * 2;   // Yb
  unsigned short* WtE = (unsigned short*)p; p += (size_t)512 * 256 * 2;
  unsigned short* Wt1 = (unsigned short*)p; p += (size_t)3 * 512 * 1024 * 2;
  unsigned short* Wt2 = (unsigned short*)p; p += (size_t)3 * 512 * 1024 * 2;
  float* hg     = (float*)p; p += (size_t)N_GRAPH * HID * 4;
  float* sums   = (float*)p; p += 1024 * 4;
  float* invdeg = (float*)p; p += (size_t)N_NODES * 4;
  float* bcnt   = (float*)p; p += 256;
  int* deg      = (int*)p;   p += (size_t)N_NODES * 4;
  int* fillc    = (int*)p;   p += (size_t)N_NODES * 4;
  int* esrc     = (int*)p;   p += (size_t)N_EDGES * 4;
  int* rowptr   = (int*)p;   p += (size_t)(N_NODES + 1) * 4;
  int* bsum     = (int*)p;   p += (size_t)NB * 4;
  size_t need = (size_t)(p - (char*)d_ws);
  if (ws_size < need) {
    write_sentinel<<<1, 1, 0, stream>>>(out, (float)need);
    return;
  }
  // optional 4th activation buffer -> SAGE2 also runs as a single gemm_dual
  unsigned short* B3 = nullptr;
  if (ws_size >= need + NS * 2) B3 = (unsigned short*)((char*)d_ws + need);

  // ---- weight prep (fp32 -> bf16, transposed [N][K]); layer-batched
  wtrans<<<dim3(8, 16, 1), 256, 0, stream>>>(W_embed, WtE, 256, 512, 0, 0);
  wtrans<<<dim3(32, 16, 3), 256, 0, stream>>>(W1, Wt1, 1024, 512,
                                              (size_t)1024 * 512, (size_t)512 * 1024);
  wtrans<<<dim3(32, 16, 3), 256, 0, stream>>>(W2, Wt2, 1024, 512,
                                              (size_t)1024 * 512, (size_t)512 * 1024);

  // ---- CSR build (parallel scan)
  hipMemsetAsync(deg, 0, N_NODES * sizeof(int), stream);
  hipMemsetAsync(fillc, 0, N_NODES * sizeof(int), stream);
  count_deg<<<(N_EDGES + 255) / 256, 256, 0, stream>>>(dstIdx, deg, N_EDGES);
  make_invdeg<<<(N_NODES + 255) / 256, 256, 0, stream>>>(deg, invdeg, N_NODES);
  scan_part<<<NB, 256, 0, stream>>>(deg, bsum, N_NODES);
  scan_bsums<<<1, 256, 0, stream>>>(bsum, NB);
  scan_final<<<NB, 256, 0, stream>>>(deg, bsum, rowptr, N_NODES);
  fill_csr<<<(N_EDGES + 255) / 256, 256, 0, stream>>>(srcIdx, dstIdx, rowptr, fillc,
                                                      esrc, N_EDGES);

  const int g1grid = 8 * 59 * 4;  // single-output GEMM grid (1888)
  const int g2grid = 8 * 59 * 8;  // dual-output GEMM grid (3776)
  const int sgrid  = (N_NODES + 63) / 64;
  const int ngrid  = (N_NODES + 3) / 4;     // aggr_norm: one wave per node
  const int bgrid  = (N_NODES + 31) / 32;   // bn_stats: 32 rows/block
  const int egrid  = (int)((NS / 8 + 255) / 256);

  // ---- embed: x -> bf16 (B1), then h = x @ W_embed -> B0
  cvt_bf16<<<(int)(((size_t)N_NODES * 64 + 255) / 256), 256, 0, stream>>>(
      x, B1, (long)N_NODES * 64);
  gemm_glds<<<g1grid, 256, 0, stream>>>(B1, 256, 256, WtE, 256, nullptr, B0, N_NODES);

  for (int l = 0; l < 3; ++l) {
    const unsigned short* Wt1l = Wt1 + (size_t)l * 512 * 1024;
    const unsigned short* Wt2l = Wt2 + (size_t)l * 512 * 1024;
    // ---- SAGE 1: B1 = Ya+bias, B2 = Yb (one fused launch)
    gemm_dual<<<g2grid, 256, 0, stream>>>(B0, 512, Wt1l, b1 + l * 512, B1, B2, N_NODES);
    aggr_norm<<<ngrid, 256, 0, stream>>>(B1, B2, rowptr, esrc, invdeg, N_NODES);
    hipMemsetAsync(sums, 0, 1024 * sizeof(float), stream);
    bn_stats<<<bgrid, 256, 0, stream>>>(B1, N_NODES, sums);
    bn_apply<<<egrid, 256, 0, stream>>>(B1, B1, sums, g1 + l * 512,
                                        be1 + l * 512, N_NODES, 0);
    // ---- SAGE 2 + residual
    unsigned short* Ya2 = B3 ? B3 : B1;
    if (B3) {
      gemm_dual<<<g2grid, 256, 0, stream>>>(B1, 512, Wt2l, b2 + l * 512, B3, B2,
                                            N_NODES);
    } else {
      gemm_glds<<<g1grid, 256, 0, stream>>>(B1, 512, 512, Wt2l + 512, 1024,
                                            nullptr, B2, N_NODES);       // Yb
      gemm_strip<<<sgrid, 512, 0, stream>>>(B1, 512, Wt2l, 1024,
                                            b2 + l * 512, B1, N_NODES);  // Ya in-place
    }
    aggr_norm<<<ngrid, 256, 0, stream>>>(Ya2, B2, rowptr, esrc, invdeg, N_NODES);
    hipMemsetAsync(sums, 0, 1024 * sizeof(float), stream);
    bn_stats<<<bgrid, 256, 0, stream>>>(Ya2, N_NODES, sums);
    bn_apply<<<egrid, 256, 0, stream>>>(Ya2, B0, sums, g2 + l * 512,
                                        be2 + l * 512, N_NODES, 1);
  }

  // ---- pooling + readout
  hipMemsetAsync(hg, 0, (size_t)N_GRAPH * HID * sizeof(float), stream);
  hipMemsetAsync(bcnt, 0, N_GRAPH * sizeof(float), stream);
  bcount<<<NB, 256, 0, stream>>>(batch, bcnt, N_NODES);
  att_pool2<<<(N_NODES + NPB - 1) / NPB, 256, 0, stream>>>(B0, batch, Watt, hg, N_NODES);
  readout<<<dim3(N_GRAPH, 4), 256, 0, stream>>>(hg, bcnt, Wread, out);
}